// Round 1
// baseline (893.490 us; speedup 1.0000x reference)
//
#include <hip/hip_runtime.h>
#include <math.h>

#define N_NODES 50000
#define N_EDGES 800000
#define NGRAPHS 50
#define NHEADS 3
#define EPS 1e-5f

// ------------------------------------------------------------------ setup
__global__ void __launch_bounds__(256) k_zero_setup(int* cnt, int* cur, float* gsum, float* gcnt) {
  int gid = blockIdx.x * 256 + threadIdx.x;
  int gs = gridDim.x * 256;
  for (int i = gid; i < N_NODES; i += gs) { cnt[i] = 0; cur[i] = 0; }
  for (int i = gid; i < NGRAPHS * 64; i += gs) gsum[i] = 0.f;
  for (int i = gid; i < NGRAPHS; i += gs) gcnt[i] = 0.f;
}

__global__ void __launch_bounds__(64) k_scalars(const float* dh, int nbins, float* scal) {
  int t = threadIdx.x;
  float v = (t < nbins) ? dh[t] : 0.f;
  float lv = logf((float)t + 1.f) * v;
  float bv = (float)t * v;
  for (int d = 32; d > 0; d >>= 1) {
    v  += __shfl_down(v,  d, 64);
    lv += __shfl_down(lv, d, 64);
    bv += __shfl_down(bv, d, 64);
  }
  if (t == 0) { scal[0] = lv / v; scal[1] = bv / v; }  // avg_log, avg_lin
}

__global__ void __launch_bounds__(256) k_hist(const int* __restrict__ dst, int* __restrict__ cnt) {
  int e = blockIdx.x * 256 + threadIdx.x;
  if (e < N_EDGES) atomicAdd(&cnt[dst[e]], 1);
}

__global__ void __launch_bounds__(256) k_scan_a(const int* __restrict__ cnt, int* __restrict__ off,
                                                int* __restrict__ blksum) {
  __shared__ int lds[256];
  int t = threadIdx.x;
  int base = blockIdx.x * 1024 + t * 4;
  int v0 = (base + 0 < N_NODES) ? cnt[base + 0] : 0;
  int v1 = (base + 1 < N_NODES) ? cnt[base + 1] : 0;
  int v2 = (base + 2 < N_NODES) ? cnt[base + 2] : 0;
  int v3 = (base + 3 < N_NODES) ? cnt[base + 3] : 0;
  int tsum = v0 + v1 + v2 + v3;
  lds[t] = tsum; __syncthreads();
  for (int d = 1; d < 256; d <<= 1) {
    int x = (t >= d) ? lds[t - d] : 0;
    __syncthreads();
    lds[t] += x;
    __syncthreads();
  }
  int run = lds[t] - tsum;  // exclusive prefix within block
  if (base + 0 < N_NODES) off[base + 0] = run; run += v0;
  if (base + 1 < N_NODES) off[base + 1] = run; run += v1;
  if (base + 2 < N_NODES) off[base + 2] = run; run += v2;
  if (base + 3 < N_NODES) off[base + 3] = run;
  if (t == 255) blksum[blockIdx.x] = lds[255];
}

__global__ void __launch_bounds__(64) k_scan_b(const int* __restrict__ blksum, int* __restrict__ blkoff) {
  int t = threadIdx.x;
  int own = (t < 49) ? blksum[t] : 0;
  int v = own;
  for (int d = 1; d < 64; d <<= 1) {
    int u = __shfl_up(v, d, 64);
    if (t >= d) v += u;
  }
  if (t < 49) blkoff[t] = v - own;
}

__global__ void __launch_bounds__(256) k_scan_c(int* __restrict__ off, const int* __restrict__ blkoff) {
  int i = blockIdx.x * 256 + threadIdx.x;
  if (i < N_NODES) off[i] += blkoff[i >> 10];
  if (i == 0) off[N_NODES] = N_EDGES;
}

__global__ void __launch_bounds__(256) k_scatter(const int* __restrict__ src, const int* __restrict__ dst,
                                                 const int* __restrict__ off, int* __restrict__ cur,
                                                 int* __restrict__ esrc) {
  int e = blockIdx.x * 256 + threadIdx.x;
  if (e < N_EDGES) {
    int d = dst[e];
    int pos = off[d] + atomicAdd(&cur[d], 1);
    esrc[pos] = src[e];
  }
}

// ------------------------------------------------------------ K=64 GEMM (GEMM1 / GEMM3)
// NCOL=128: W is preW [128][64], out cols 0..63 = x@preW[0:64]+bias, 64..127 = x@preW[64:128]
// NCOL=64 : W is [64][64], bias applied to all cols
template <int NCOL>
__global__ void __launch_bounds__(256) k_gemm_k64(const float* __restrict__ xin, const float* __restrict__ W,
                                                  const float* __restrict__ bias, float* __restrict__ out, int M) {
  constexpr int CPT = NCOL / 16;  // 8 or 4 cols per thread
  __shared__ float xS[64][68];
  __shared__ float Wg[64 * NCOL];
  __shared__ float biasS[NCOL];
  int t = threadIdx.x;
  int rb = t >> 4, cb = t & 15;
  int r0 = blockIdx.x * 64;
  if (t < NCOL) biasS[t] = (t < 64) ? bias[t] : 0.f;
  // stage x tile (64 rows x 64 k), clamped rows
  for (int i = 0; i < 4; ++i) {
    int lin = t + 256 * i;
    int row = lin >> 4, c4 = lin & 15;
    int rsrc = min(r0 + row, M - 1);
    *(float4*)(&xS[row][c4 * 4]) = *(const float4*)(xin + (size_t)rsrc * 64 + c4 * 4);
  }
  // stage weights
  constexpr int WF4 = 64 * NCOL / 4;
  for (int i = 0; i < WF4 / 256; ++i) {
    int lin = t + 256 * i;
    if (NCOL == 128) {
      int k = lin >> 5, c4 = lin & 31;
      int j = c4 * 4;
      const float* s = (j < 64) ? (W + k * 64 + j) : (W + (64 + k) * 64 + (j - 64));
      *(float4*)(&Wg[k * NCOL + j]) = *(const float4*)s;
    } else {
      int k = lin >> 4, c4 = lin & 15;
      *(float4*)(&Wg[k * NCOL + c4 * 4]) = *(const float4*)(W + k * NCOL + c4 * 4);
    }
  }
  __syncthreads();
  float acc[4][CPT];
  #pragma unroll
  for (int ri = 0; ri < 4; ++ri)
    #pragma unroll
    for (int c = 0; c < CPT; ++c) acc[ri][c] = 0.f;
  for (int k = 0; k < 64; ++k) {
    float a[4];
    #pragma unroll
    for (int ri = 0; ri < 4; ++ri) a[ri] = xS[rb * 4 + ri][k];
    #pragma unroll
    for (int u = 0; u < CPT / 4; ++u) {
      float4 w = *(const float4*)(&Wg[k * NCOL + cb * CPT + u * 4]);
      #pragma unroll
      for (int ri = 0; ri < 4; ++ri) {
        acc[ri][u * 4 + 0] += a[ri] * w.x;
        acc[ri][u * 4 + 1] += a[ri] * w.y;
        acc[ri][u * 4 + 2] += a[ri] * w.z;
        acc[ri][u * 4 + 3] += a[ri] * w.w;
      }
    }
  }
  #pragma unroll
  for (int ri = 0; ri < 4; ++ri) {
    int r = r0 + rb * 4 + ri;
    if (r < M) {
      #pragma unroll
      for (int u = 0; u < CPT / 4; ++u) {
        int j = cb * CPT + u * 4;
        float4 o;
        o.x = acc[ri][u * 4 + 0] + biasS[j + 0];
        o.y = acc[ri][u * 4 + 1] + biasS[j + 1];
        o.z = acc[ri][u * 4 + 2] + biasS[j + 2];
        o.w = acc[ri][u * 4 + 3] + biasS[j + 3];
        *(float4*)(out + (size_t)r * NCOL + j) = o;
      }
    }
  }
}

// ------------------------------------------------------------ aggregation (1 wave per node)
__global__ void __launch_bounds__(256) k_aggr(const float* __restrict__ AB, const int* __restrict__ off,
                                              const int* __restrict__ esrc, float* __restrict__ aggr) {
  int wave = threadIdx.x >> 6, lane = threadIdx.x & 63;
  int n = blockIdx.x * 4 + wave;
  if (n >= N_NODES) return;
  float c = AB[(size_t)n * 128 + lane];  // A part, includes preb
  int e0 = off[n], e1 = off[n + 1];
  int deg = e1 - e0;
  float sum = 0.f, sq = 0.f, mn = 3.4e38f, mx = -3.4e38f;
  int e = e0;
  for (; e + 1 < e1; e += 2) {
    int s0 = esrc[e], s1 = esrc[e + 1];
    float b0 = AB[(size_t)s0 * 128 + 64 + lane];
    float b1 = AB[(size_t)s1 * 128 + 64 + lane];
    sum += b0 + b1; sq += b0 * b0 + b1 * b1;
    mn = fminf(mn, fminf(b0, b1)); mx = fmaxf(mx, fmaxf(b0, b1));
  }
  if (e < e1) {
    int s = esrc[e];
    float b = AB[(size_t)s * 128 + 64 + lane];
    sum += b; sq += b * b; mn = fminf(mn, b); mx = fmaxf(mx, b);
  }
  float* arow = aggr + (size_t)n * 256;
  if (deg == 0) {
    arow[lane] = 0.f; arow[64 + lane] = 0.f; arow[128 + lane] = 0.f; arow[192 + lane] = sqrtf(EPS);
  } else {
    float inv = 1.f / (float)deg;
    float mb = sum * inv, m2 = sq * inv;
    float var = fmaxf(m2 - mb * mb, 0.f);
    arow[lane]       = c + mb;
    arow[64 + lane]  = c + mn;
    arow[128 + lane] = c + mx;
    arow[192 + lane] = sqrtf(var + EPS);
  }
}

// ------------------------------------------------------------ GEMM2: y = x@Wx + aggr@(W1+s1W2+s2W3+s3W4) + postb
__global__ void __launch_bounds__(256) k_gemm2(const float* __restrict__ aggr, const float* __restrict__ xin,
                                               const float* __restrict__ postW, const float* __restrict__ postb,
                                               const int* __restrict__ cnt, const float* __restrict__ scal,
                                               float* __restrict__ ybuf) {
  __shared__ float aS[64][36];
  __shared__ float Wc[4 * 32 * 64];
  __shared__ float sP[3][64];
  int t = threadIdx.x, rb = t >> 4, cb = t & 15;
  int r0 = blockIdx.x * 64;
  if (t < 64) {
    int r = min(r0 + t, N_NODES - 1);
    float degf = fmaxf((float)cnt[r], 1.f);
    float ld = logf(degf + 1.f);
    float al = scal[0], av = scal[1];
    sP[0][t] = ld / al;
    sP[1][t] = al / ld;
    sP[2][t] = degf / av;
  }
  float acc[4][4][4];  // [set][ri][cj]
  #pragma unroll
  for (int s = 0; s < 4; ++s)
    #pragma unroll
    for (int ri = 0; ri < 4; ++ri)
      #pragma unroll
      for (int c = 0; c < 4; ++c) acc[s][ri][c] = 0.f;
  // phase A: aggr K=256 in 8 chunks of 32, 4 weight sets
  for (int kc = 0; kc < 8; ++kc) {
    __syncthreads();
    for (int i = 0; i < 2; ++i) {
      int lin = t + 256 * i;
      int row = lin >> 3, c4 = lin & 7;
      int rsrc = min(r0 + row, N_NODES - 1);
      *(float4*)(&aS[row][c4 * 4]) = *(const float4*)(aggr + (size_t)rsrc * 256 + kc * 32 + c4 * 4);
    }
    for (int i = 0; i < 8; ++i) {
      int lin = t + 256 * i;
      int s = lin >> 9, rem = lin & 511, k = rem >> 4, c4 = rem & 15;
      *(float4*)(&Wc[(s * 32 + k) * 64 + c4 * 4]) =
          *(const float4*)(postW + (size_t)(64 + s * 256 + kc * 32 + k) * 64 + c4 * 4);
    }
    __syncthreads();
    for (int k = 0; k < 32; ++k) {
      float a[4];
      #pragma unroll
      for (int ri = 0; ri < 4; ++ri) a[ri] = aS[rb * 4 + ri][k];
      #pragma unroll
      for (int s = 0; s < 4; ++s) {
        float4 w = *(const float4*)(&Wc[(s * 32 + k) * 64 + cb * 4]);
        #pragma unroll
        for (int ri = 0; ri < 4; ++ri) {
          acc[s][ri][0] += a[ri] * w.x;
          acc[s][ri][1] += a[ri] * w.y;
          acc[s][ri][2] += a[ri] * w.z;
          acc[s][ri][3] += a[ri] * w.w;
        }
      }
    }
  }
  // phase B: x K=64 in 2 chunks of 32 -> acc[0]
  for (int kc = 0; kc < 2; ++kc) {
    __syncthreads();
    for (int i = 0; i < 2; ++i) {
      int lin = t + 256 * i;
      int row = lin >> 3, c4 = lin & 7;
      int rsrc = min(r0 + row, N_NODES - 1);
      *(float4*)(&aS[row][c4 * 4]) = *(const float4*)(xin + (size_t)rsrc * 64 + kc * 32 + c4 * 4);
    }
    for (int i = 0; i < 2; ++i) {
      int lin = t + 256 * i;
      int k = lin >> 4, c4 = lin & 15;
      *(float4*)(&Wc[k * 64 + c4 * 4]) = *(const float4*)(postW + (size_t)(kc * 32 + k) * 64 + c4 * 4);
    }
    __syncthreads();
    for (int k = 0; k < 32; ++k) {
      float a[4];
      #pragma unroll
      for (int ri = 0; ri < 4; ++ri) a[ri] = aS[rb * 4 + ri][k];
      float4 w = *(const float4*)(&Wc[k * 64 + cb * 4]);
      #pragma unroll
      for (int ri = 0; ri < 4; ++ri) {
        acc[0][ri][0] += a[ri] * w.x;
        acc[0][ri][1] += a[ri] * w.y;
        acc[0][ri][2] += a[ri] * w.z;
        acc[0][ri][3] += a[ri] * w.w;
      }
    }
  }
  float4 pb = *(const float4*)(postb + cb * 4);
  #pragma unroll
  for (int ri = 0; ri < 4; ++ri) {
    int rr = rb * 4 + ri, r = r0 + rr;
    if (r < N_NODES) {
      float s1 = sP[0][rr], s2 = sP[1][rr], s3 = sP[2][rr];
      float4 o;
      o.x = acc[0][ri][0] + s1 * acc[1][ri][0] + s2 * acc[2][ri][0] + s3 * acc[3][ri][0] + pb.x;
      o.y = acc[0][ri][1] + s1 * acc[1][ri][1] + s2 * acc[2][ri][1] + s3 * acc[3][ri][1] + pb.y;
      o.z = acc[0][ri][2] + s1 * acc[1][ri][2] + s2 * acc[2][ri][2] + s3 * acc[3][ri][2] + pb.z;
      o.w = acc[0][ri][3] + s1 * acc[1][ri][3] + s2 * acc[2][ri][3] + s3 * acc[3][ri][3] + pb.w;
      *(float4*)(ybuf + (size_t)r * 64 + cb * 4) = o;
    }
  }
}

// ------------------------------------------------------------ BatchNorm
__global__ void __launch_bounds__(256) k_bnstats(const float* __restrict__ y, float* __restrict__ part,
                                                 float* __restrict__ partq) {
  __shared__ float ls[256], lq[256];
  int t = threadIdx.x, col = t & 63, rl = t >> 6;
  float s = 0.f, q = 0.f;
  for (int r = blockIdx.x * 4 + rl; r < N_NODES; r += 128 * 4) {
    float v = y[(size_t)r * 64 + col];
    s += v; q += v * v;
  }
  ls[t] = s; lq[t] = q; __syncthreads();
  if (rl == 0) {
    s = ls[col] + ls[64 + col] + ls[128 + col] + ls[192 + col];
    q = lq[col] + lq[64 + col] + lq[128 + col] + lq[192 + col];
    part[blockIdx.x * 64 + col] = s;
    partq[blockIdx.x * 64 + col] = q;
  }
}

__global__ void __launch_bounds__(64) k_bnfinal(const float* __restrict__ part, const float* __restrict__ partq,
                                                const float* __restrict__ g, const float* __restrict__ b,
                                                float* __restrict__ scale, float* __restrict__ shift) {
  int j = threadIdx.x;
  float s = 0.f, q = 0.f;
  for (int i = 0; i < 128; ++i) { s += part[i * 64 + j]; q += partq[i * 64 + j]; }
  float m = s / (float)N_NODES;
  float v = fmaxf(q / (float)N_NODES - m * m, 0.f);
  float sc = g[j] * rsqrtf(v + EPS);
  scale[j] = sc;
  shift[j] = b[j] - m * sc;
}

__global__ void __launch_bounds__(256) k_bnapply(const float* __restrict__ y, const float* __restrict__ scale,
                                                 const float* __restrict__ shift, float* __restrict__ xout) {
  int gid = blockIdx.x * 256 + threadIdx.x;  // float4 index
  if (gid < N_NODES * 16) {
    int c4 = gid & 15;
    float4 v = ((const float4*)y)[gid];
    float4 sc = ((const float4*)scale)[c4];
    float4 sh = ((const float4*)shift)[c4];
    float4 o;
    o.x = fmaxf(v.x * sc.x + sh.x, 0.f);
    o.y = fmaxf(v.y * sc.y + sh.y, 0.f);
    o.z = fmaxf(v.z * sc.z + sh.z, 0.f);
    o.w = fmaxf(v.w * sc.w + sh.w, 0.f);
    ((float4*)xout)[gid] = o;
  }
}

// ------------------------------------------------------------ pooling + head MLPs
__global__ void __launch_bounds__(256) k_pool(const float* __restrict__ x, const int* __restrict__ batch,
                                              float* __restrict__ gsum, float* __restrict__ gcnt) {
  int t = threadIdx.x, col = t & 63, rl = t >> 6;
  int rbeg = blockIdx.x * 64 + rl * 16;
  int rend = min(rbeg + 16, N_NODES);
  int curg = -1, cr = 0;
  float acc = 0.f;
  for (int r = rbeg; r < rend; ++r) {
    int g = batch[r];
    if (g != curg) {
      if (curg >= 0) {
        atomicAdd(&gsum[curg * 64 + col], acc);
        if (col == 0) atomicAdd(&gcnt[curg], (float)cr);
      }
      curg = g; acc = 0.f; cr = 0;
    }
    acc += x[(size_t)r * 64 + col]; cr++;
  }
  if (curg >= 0) {
    atomicAdd(&gsum[curg * 64 + col], acc);
    if (col == 0) atomicAdd(&gcnt[curg], (float)cr);
  }
}

__global__ void __launch_bounds__(64) k_shared(const float* __restrict__ gsum, const float* __restrict__ gcnt,
                                               const float* __restrict__ W, const float* __restrict__ b,
                                               float* __restrict__ g2) {
  __shared__ float gm[64];
  int g = blockIdx.x, j = threadIdx.x;
  float cv = fmaxf(gcnt[g], 1.f);
  gm[j] = gsum[g * 64 + j] / cv;
  __syncthreads();
  float s = b[j];
  for (int k = 0; k < 64; ++k) s += gm[k] * W[k * 64 + j];
  g2[g * 64 + j] = fmaxf(s, 0.f);
}

__global__ void __launch_bounds__(64) k_heads(const float* __restrict__ g2, const float* __restrict__ hW1,
                                              const float* __restrict__ hb1, const float* __restrict__ hW2,
                                              const float* __restrict__ hb2, const float* __restrict__ hW3,
                                              const float* __restrict__ hb3, float* __restrict__ out) {
  __shared__ float gv[64], h1[50], h2[25];
  int bid = blockIdx.x;
  int g = bid / NHEADS, h = bid % NHEADS;
  int t = threadIdx.x;
  gv[t] = g2[g * 64 + t];
  __syncthreads();
  if (t < 50) {
    float s = hb1[h * 50 + t];
    for (int k = 0; k < 64; ++k) s += gv[k] * hW1[h * 3200 + k * 50 + t];
    h1[t] = fmaxf(s, 0.f);
  }
  __syncthreads();
  if (t < 25) {
    float s = hb2[h * 25 + t];
    for (int k = 0; k < 50; ++k) s += h1[k] * hW2[h * 1250 + k * 25 + t];
    h2[t] = fmaxf(s, 0.f);
  }
  __syncthreads();
  if (t == 0) {
    float s = hb3[h];
    for (int k = 0; k < 25; ++k) s += h2[k] * hW3[h * 25 + k];
    out[g * NHEADS + h] = s;
  }
}

// ------------------------------------------------------------ launcher
extern "C" void kernel_launch(void* const* d_in, const int* in_sizes, int n_in,
                              void* d_out, int out_size, void* d_ws, size_t ws_size,
                              hipStream_t stream) {
  const float* x0    = (const float*)d_in[0];
  const int*   eidx  = (const int*)d_in[1];
  const int*   batch = (const int*)d_in[2];
  const float* dh    = (const float*)d_in[3];
  const float* preW  = (const float*)d_in[4];
  const float* preb  = (const float*)d_in[5];
  const float* postW = (const float*)d_in[6];
  const float* postb = (const float*)d_in[7];
  const float* linW  = (const float*)d_in[8];
  const float* linb  = (const float*)d_in[9];
  const float* bng   = (const float*)d_in[10];
  const float* bnb   = (const float*)d_in[11];
  const float* shW   = (const float*)d_in[12];
  const float* shb   = (const float*)d_in[13];
  const float* hW1   = (const float*)d_in[14];
  const float* hb1   = (const float*)d_in[15];
  const float* hW2   = (const float*)d_in[16];
  const float* hb2   = (const float*)d_in[17];
  const float* hW3   = (const float*)d_in[18];
  const float* hb3   = (const float*)d_in[19];
  float* out = (float*)d_out;

  char* ws = (char*)d_ws;
  size_t o = 0;
  auto alloc = [&](size_t bytes) {
    char* p = ws + o;
    o = (o + bytes + 255) & ~(size_t)255;
    return p;
  };
  float* scal  = (float*)alloc(8 * 4);
  int* off     = (int*)alloc((N_NODES + 1) * 4);
  int* cnt     = (int*)alloc(N_NODES * 4);
  int* cur     = (int*)alloc(N_NODES * 4);
  int* esrc    = (int*)alloc(N_EDGES * 4);
  int* blks    = (int*)alloc(64 * 4);
  int* blko    = (int*)alloc(64 * 4);
  float* AB    = (float*)alloc((size_t)N_NODES * 128 * 4);
  float* aggr  = (float*)alloc((size_t)N_NODES * 256 * 4);
  float* xb0   = (float*)alloc((size_t)N_NODES * 64 * 4);
  float* xb1   = (float*)alloc((size_t)N_NODES * 64 * 4);
  float* ybuf  = (float*)alloc((size_t)N_NODES * 64 * 4);
  float* part  = (float*)alloc(128 * 64 * 4);
  float* partq = (float*)alloc(128 * 64 * 4);
  float* bnsc  = (float*)alloc(64 * 4);
  float* bnsh  = (float*)alloc(64 * 4);
  float* gsum  = (float*)alloc(NGRAPHS * 64 * 4);
  float* gcnt  = (float*)alloc(NGRAPHS * 4);
  float* g2    = (float*)alloc(NGRAPHS * 64 * 4);
  float* y2    = AB;  // alias: AB dead after k_aggr each layer

  const int* srcv = eidx;
  const int* dstv = eidx + N_EDGES;

  k_zero_setup<<<256, 256, 0, stream>>>(cnt, cur, gsum, gcnt);
  k_scalars<<<1, 64, 0, stream>>>(dh, in_sizes[3], scal);
  k_hist<<<(N_EDGES + 255) / 256, 256, 0, stream>>>(dstv, cnt);
  k_scan_a<<<49, 256, 0, stream>>>(cnt, off, blks);
  k_scan_b<<<1, 64, 0, stream>>>(blks, blko);
  k_scan_c<<<196, 256, 0, stream>>>(off, blko);
  k_scatter<<<(N_EDGES + 255) / 256, 256, 0, stream>>>(srcv, dstv, off, cur, esrc);

  const float* xc = x0;
  float* xn[3] = {xb0, xb1, xb0};
  for (int l = 0; l < 3; ++l) {
    k_gemm_k64<128><<<782, 256, 0, stream>>>(xc, preW + (size_t)l * 128 * 64, preb + l * 64, AB, N_NODES);
    k_aggr<<<12500, 256, 0, stream>>>(AB, off, esrc, aggr);
    k_gemm2<<<782, 256, 0, stream>>>(aggr, xc, postW + (size_t)l * 1088 * 64, postb + l * 64, cnt, scal, ybuf);
    k_gemm_k64<64><<<782, 256, 0, stream>>>(ybuf, linW + (size_t)l * 64 * 64, linb + l * 64, y2, N_NODES);
    k_bnstats<<<128, 256, 0, stream>>>(y2, part, partq);
    k_bnfinal<<<1, 64, 0, stream>>>(part, partq, bng + l * 64, bnb + l * 64, bnsc, bnsh);
    k_bnapply<<<3125, 256, 0, stream>>>(y2, bnsc, bnsh, xn[l]);
    xc = xn[l];
  }
  k_pool<<<782, 256, 0, stream>>>(xc, batch, gsum, gcnt);
  k_shared<<<NGRAPHS, 64, 0, stream>>>(gsum, gcnt, shW, shb, g2);
  k_heads<<<NGRAPHS * NHEADS, 64, 0, stream>>>(g2, hW1, hb1, hW2, hb2, hW3, hb3, out);
}

// Round 2
// 653.717 us; speedup vs baseline: 1.3668x; 1.3668x over previous
//
#include <hip/hip_runtime.h>
#include <math.h>

#define N_NODES 50000
#define N_EDGES 800000
#define NGRAPHS 50
#define NHEADS 3
#define EPS 1e-5f

typedef _Float16 half8 __attribute__((ext_vector_type(8)));
typedef float f32x4 __attribute__((ext_vector_type(4)));

// ------------------------------------------------------------------ setup
__global__ void __launch_bounds__(256) k_zero_setup(int* cnt, int* cur, float* gsum, float* gcnt) {
  int gid = blockIdx.x * 256 + threadIdx.x;
  int gs = gridDim.x * 256;
  for (int i = gid; i < N_NODES; i += gs) { cnt[i] = 0; cur[i] = 0; }
  for (int i = gid; i < NGRAPHS * 64; i += gs) gsum[i] = 0.f;
  for (int i = gid; i < NGRAPHS; i += gs) gcnt[i] = 0.f;
}

__global__ void __launch_bounds__(64) k_scalars(const float* dh, int nbins, float* scal) {
  int t = threadIdx.x;
  float v = (t < nbins) ? dh[t] : 0.f;
  float lv = logf((float)t + 1.f) * v;
  float bv = (float)t * v;
  for (int d = 32; d > 0; d >>= 1) {
    v  += __shfl_down(v,  d, 64);
    lv += __shfl_down(lv, d, 64);
    bv += __shfl_down(bv, d, 64);
  }
  if (t == 0) { scal[0] = lv / v; scal[1] = bv / v; }  // avg_log, avg_lin
}

__global__ void __launch_bounds__(256) k_hist(const int* __restrict__ dst, int* __restrict__ cnt) {
  int e = blockIdx.x * 256 + threadIdx.x;
  if (e < N_EDGES) atomicAdd(&cnt[dst[e]], 1);
}

__global__ void __launch_bounds__(256) k_scan_a(const int* __restrict__ cnt, int* __restrict__ off,
                                                int* __restrict__ blksum) {
  __shared__ int lds[256];
  int t = threadIdx.x;
  int base = blockIdx.x * 1024 + t * 4;
  int v0 = (base + 0 < N_NODES) ? cnt[base + 0] : 0;
  int v1 = (base + 1 < N_NODES) ? cnt[base + 1] : 0;
  int v2 = (base + 2 < N_NODES) ? cnt[base + 2] : 0;
  int v3 = (base + 3 < N_NODES) ? cnt[base + 3] : 0;
  int tsum = v0 + v1 + v2 + v3;
  lds[t] = tsum; __syncthreads();
  for (int d = 1; d < 256; d <<= 1) {
    int x = (t >= d) ? lds[t - d] : 0;
    __syncthreads();
    lds[t] += x;
    __syncthreads();
  }
  int run = lds[t] - tsum;
  if (base + 0 < N_NODES) off[base + 0] = run; run += v0;
  if (base + 1 < N_NODES) off[base + 1] = run; run += v1;
  if (base + 2 < N_NODES) off[base + 2] = run; run += v2;
  if (base + 3 < N_NODES) off[base + 3] = run;
  if (t == 255) blksum[blockIdx.x] = lds[255];
}

__global__ void __launch_bounds__(64) k_scan_b(const int* __restrict__ blksum, int* __restrict__ blkoff) {
  int t = threadIdx.x;
  int own = (t < 49) ? blksum[t] : 0;
  int v = own;
  for (int d = 1; d < 64; d <<= 1) {
    int u = __shfl_up(v, d, 64);
    if (t >= d) v += u;
  }
  if (t < 49) blkoff[t] = v - own;
}

__global__ void __launch_bounds__(256) k_scan_c(int* __restrict__ off, const int* __restrict__ blkoff) {
  int i = blockIdx.x * 256 + threadIdx.x;
  if (i < N_NODES) off[i] += blkoff[i >> 10];
  if (i == 0) off[N_NODES] = N_EDGES;
}

__global__ void __launch_bounds__(256) k_scatter(const int* __restrict__ src, const int* __restrict__ dst,
                                                 const int* __restrict__ off, int* __restrict__ cur,
                                                 int* __restrict__ esrc) {
  int e = blockIdx.x * 256 + threadIdx.x;
  if (e < N_EDGES) {
    int d = dst[e];
    int pos = off[d] + atomicAdd(&cur[d], 1);
    esrc[pos] = src[e];
  }
}

// ------------------------------------------------------------------ fp32 -> fp16 convert (x0)
__global__ void __launch_bounds__(256) k_f2h(const float* __restrict__ xin, _Float16* __restrict__ xout) {
  int t = blockIdx.x * 256 + threadIdx.x;  // one thread = 8 elems
  if (t < N_NODES * 8) {
    const float* s = xin + (size_t)t * 8;
    float4 v0 = *(const float4*)s;
    float4 v1 = *(const float4*)(s + 4);
    half8 h = {(_Float16)v0.x, (_Float16)v0.y, (_Float16)v0.z, (_Float16)v0.w,
               (_Float16)v1.x, (_Float16)v1.y, (_Float16)v1.z, (_Float16)v1.w};
    *(half8*)(xout + (size_t)t * 8) = h;
  }
}

// ------------------------------------------------------------------ weight packing into b-frag order
// b-frag element (lane, j): k = kbase + (lane>>4)*8 + j, col = cbase + (lane&15)
__global__ void __launch_bounds__(256) k_pack_pre(const float* __restrict__ preW, _Float16* __restrict__ wp) {
  int t = blockIdx.x * 256 + threadIdx.x;  // 3 * 8192
  if (t >= 3 * 8192) return;
  int l = t >> 13, r = t & 8191;
  int j = r & 7, lane = (r >> 3) & 63, ctg = (r >> 9) & 7, kc = r >> 12;
  int k = kc * 32 + ((lane >> 4) << 3) + j;
  int col = ctg * 16 + (lane & 15);
  const float* W = preW + (size_t)l * 8192;
  float v = (col < 64) ? W[k * 64 + col] : W[(64 + k) * 64 + (col - 64)];
  wp[(size_t)l * 8192 + r] = (_Float16)v;
}

__global__ void __launch_bounds__(256) k_pack_postA(const float* __restrict__ postW, _Float16* __restrict__ wp) {
  int t = blockIdx.x * 256 + threadIdx.x;  // 3 * 65536
  if (t >= 3 * 65536) return;
  int l = t >> 16, r = t & 65535;
  int j = r & 7, lane = (r >> 3) & 63, ct = (r >> 9) & 3, s = (r >> 11) & 3, kc = r >> 13;
  int k = kc * 32 + ((lane >> 4) << 3) + j;
  int col = ct * 16 + (lane & 15);
  wp[(size_t)l * 65536 + r] = (_Float16)postW[(size_t)l * 69632 + (size_t)(64 + s * 256 + k) * 64 + col];
}

__global__ void __launch_bounds__(256) k_pack_postB(const float* __restrict__ postW, _Float16* __restrict__ wp) {
  int t = blockIdx.x * 256 + threadIdx.x;  // 3 * 4096
  if (t >= 3 * 4096) return;
  int l = t >> 12, r = t & 4095;
  int j = r & 7, lane = (r >> 3) & 63, ct = (r >> 9) & 3, kc = r >> 11;
  int k = kc * 32 + ((lane >> 4) << 3) + j;
  int col = ct * 16 + (lane & 15);
  wp[(size_t)l * 4096 + r] = (_Float16)postW[(size_t)l * 69632 + (size_t)k * 64 + col];
}

__global__ void __launch_bounds__(256) k_pack_lin(const float* __restrict__ linW, _Float16* __restrict__ wp) {
  int t = blockIdx.x * 256 + threadIdx.x;  // 3 * 4096
  if (t >= 3 * 4096) return;
  int l = t >> 12, r = t & 4095;
  int j = r & 7, lane = (r >> 3) & 63, ct = (r >> 9) & 3, kc = r >> 11;
  int k = kc * 32 + ((lane >> 4) << 3) + j;
  int col = ct * 16 + (lane & 15);
  wp[(size_t)l * 4096 + r] = (_Float16)linW[(size_t)l * 4096 + (size_t)k * 64 + col];
}

// ------------------------------------------------------------------ GEMM1: AB[N,128] = x16 @ preW'  (fp16 out)
__global__ void __launch_bounds__(256) k_mfma_g1(const _Float16* __restrict__ x16, const _Float16* __restrict__ wp,
                                                 const float* __restrict__ bias, _Float16* __restrict__ AB) {
  int t = threadIdx.x, lane = t & 63, wave = t >> 6;
  int r0 = blockIdx.x * 64;
  int mrow = lane & 15, q8 = ((lane >> 4) << 3);
  f32x4 acc[4][2];
  #pragma unroll
  for (int rt = 0; rt < 4; ++rt) { acc[rt][0] = (f32x4)0.f; acc[rt][1] = (f32x4)0.f; }
  #pragma unroll
  for (int kc = 0; kc < 2; ++kc) {
    half8 a[4];
    #pragma unroll
    for (int rt = 0; rt < 4; ++rt) {
      int r = min(r0 + rt * 16 + mrow, N_NODES - 1);
      a[rt] = *(const half8*)(x16 + (size_t)r * 64 + kc * 32 + q8);
    }
    #pragma unroll
    for (int ci = 0; ci < 2; ++ci) {
      int ctg = wave * 2 + ci;
      half8 b = *(const half8*)(wp + (size_t)((kc * 8 + ctg) * 64 + lane) * 8);
      #pragma unroll
      for (int rt = 0; rt < 4; ++rt)
        acc[rt][ci] = __builtin_amdgcn_mfma_f32_16x16x32_f16(a[rt], b, acc[rt][ci], 0, 0, 0);
    }
  }
  #pragma unroll
  for (int ci = 0; ci < 2; ++ci) {
    int col = (wave * 2 + ci) * 16 + mrow;
    float bv = (col < 64) ? bias[col] : 0.f;
    #pragma unroll
    for (int rt = 0; rt < 4; ++rt)
      #pragma unroll
      for (int reg = 0; reg < 4; ++reg) {
        int row = r0 + rt * 16 + ((lane >> 4) << 2) + reg;
        if (row < N_NODES) AB[(size_t)row * 128 + col] = (_Float16)(acc[rt][ci][reg] + bv);
      }
  }
}

// ------------------------------------------------------------------ aggregation (1 wave/node), fp16 in/out
__global__ void __launch_bounds__(256) k_aggr(const _Float16* __restrict__ AB, const int* __restrict__ off,
                                              const int* __restrict__ esrc, const float* __restrict__ scal,
                                              _Float16* __restrict__ aggr, float4* __restrict__ scales) {
  int wave = threadIdx.x >> 6, lane = threadIdx.x & 63;
  int n = blockIdx.x * 4 + wave;
  if (n >= N_NODES) return;
  float c = (float)AB[(size_t)n * 128 + lane];
  int e0 = off[n], e1 = off[n + 1];
  int deg = e1 - e0;
  float sum = 0.f, sq = 0.f, mn = 3.4e38f, mx = -3.4e38f;
  int e = e0;
  for (; e + 1 < e1; e += 2) {
    int s0 = esrc[e], s1 = esrc[e + 1];
    float b0 = (float)AB[(size_t)s0 * 128 + 64 + lane];
    float b1 = (float)AB[(size_t)s1 * 128 + 64 + lane];
    sum += b0 + b1; sq += b0 * b0 + b1 * b1;
    mn = fminf(mn, fminf(b0, b1)); mx = fmaxf(mx, fmaxf(b0, b1));
  }
  if (e < e1) {
    int s = esrc[e];
    float b = (float)AB[(size_t)s * 128 + 64 + lane];
    sum += b; sq += b * b; mn = fminf(mn, b); mx = fmaxf(mx, b);
  }
  _Float16* arow = aggr + (size_t)n * 256;
  if (deg == 0) {
    arow[lane] = (_Float16)0.f; arow[64 + lane] = (_Float16)0.f;
    arow[128 + lane] = (_Float16)0.f; arow[192 + lane] = (_Float16)sqrtf(EPS);
  } else {
    float inv = 1.f / (float)deg;
    float mb = sum * inv, m2 = sq * inv;
    float var = fmaxf(m2 - mb * mb, 0.f);
    arow[lane]       = (_Float16)(c + mb);
    arow[64 + lane]  = (_Float16)(c + mn);
    arow[128 + lane] = (_Float16)(c + mx);
    arow[192 + lane] = (_Float16)sqrtf(var + EPS);
  }
  if (lane == 0) {
    float degf = fmaxf((float)deg, 1.f);
    float ld = logf(degf + 1.f);
    float al = scal[0], av = scal[1];
    scales[n] = make_float4(ld / al, al / ld, degf / av, 0.f);
  }
}

// ------------------------------------------------------------------ GEMM2: y = x@Wx + sum_s scale_s*(aggr@W_s) + postb
__global__ void __launch_bounds__(256) k_mfma_g2(const _Float16* __restrict__ aggr, const _Float16* __restrict__ x16,
                                                 const _Float16* __restrict__ wpA, const _Float16* __restrict__ wpB,
                                                 const float* __restrict__ postb, const float4* __restrict__ scales,
                                                 _Float16* __restrict__ ybuf) {
  int t = threadIdx.x, lane = t & 63, ct = t >> 6;
  int r0 = blockIdx.x * 64;
  int mrow = lane & 15, q8 = ((lane >> 4) << 3);
  f32x4 acc[4][4];  // [rowtile][set]
  #pragma unroll
  for (int rt = 0; rt < 4; ++rt)
    #pragma unroll
    for (int s = 0; s < 4; ++s) acc[rt][s] = (f32x4)0.f;
  // phase A: aggr K=256
  #pragma unroll 2
  for (int kc = 0; kc < 8; ++kc) {
    half8 a[4];
    #pragma unroll
    for (int rt = 0; rt < 4; ++rt) {
      int r = min(r0 + rt * 16 + mrow, N_NODES - 1);
      a[rt] = *(const half8*)(aggr + (size_t)r * 256 + kc * 32 + q8);
    }
    #pragma unroll
    for (int s = 0; s < 4; ++s) {
      half8 b = *(const half8*)(wpA + (size_t)((((kc * 4 + s) * 4 + ct) * 64) + lane) * 8);
      #pragma unroll
      for (int rt = 0; rt < 4; ++rt)
        acc[rt][s] = __builtin_amdgcn_mfma_f32_16x16x32_f16(a[rt], b, acc[rt][s], 0, 0, 0);
    }
  }
  // phase B: x K=64 -> set 0
  #pragma unroll
  for (int kc = 0; kc < 2; ++kc) {
    half8 a[4];
    #pragma unroll
    for (int rt = 0; rt < 4; ++rt) {
      int r = min(r0 + rt * 16 + mrow, N_NODES - 1);
      a[rt] = *(const half8*)(x16 + (size_t)r * 64 + kc * 32 + q8);
    }
    half8 b = *(const half8*)(wpB + (size_t)(((kc * 4 + ct) * 64) + lane) * 8);
    #pragma unroll
    for (int rt = 0; rt < 4; ++rt)
      acc[rt][0] = __builtin_amdgcn_mfma_f32_16x16x32_f16(a[rt], b, acc[rt][0], 0, 0, 0);
  }
  int col = ct * 16 + mrow;
  float pb = postb[col];
  #pragma unroll
  for (int rt = 0; rt < 4; ++rt)
    #pragma unroll
    for (int reg = 0; reg < 4; ++reg) {
      int row = r0 + rt * 16 + ((lane >> 4) << 2) + reg;
      if (row < N_NODES) {
        float4 sc = scales[row];
        float v = acc[rt][0][reg] + sc.x * acc[rt][1][reg] + sc.y * acc[rt][2][reg] + sc.z * acc[rt][3][reg] + pb;
        ybuf[(size_t)row * 64 + col] = (_Float16)v;
      }
    }
}

// ------------------------------------------------------------------ GEMM3: y2[N,64] = ybuf16 @ linW' (fp32 out)
__global__ void __launch_bounds__(256) k_mfma_g3(const _Float16* __restrict__ yin, const _Float16* __restrict__ wp,
                                                 const float* __restrict__ bias, float* __restrict__ y2) {
  int t = threadIdx.x, lane = t & 63, ct = t >> 6;
  int r0 = blockIdx.x * 64;
  int mrow = lane & 15, q8 = ((lane >> 4) << 3);
  f32x4 acc[4];
  #pragma unroll
  for (int rt = 0; rt < 4; ++rt) acc[rt] = (f32x4)0.f;
  #pragma unroll
  for (int kc = 0; kc < 2; ++kc) {
    half8 a[4];
    #pragma unroll
    for (int rt = 0; rt < 4; ++rt) {
      int r = min(r0 + rt * 16 + mrow, N_NODES - 1);
      a[rt] = *(const half8*)(yin + (size_t)r * 64 + kc * 32 + q8);
    }
    half8 b = *(const half8*)(wp + (size_t)(((kc * 4 + ct) * 64) + lane) * 8);
    #pragma unroll
    for (int rt = 0; rt < 4; ++rt)
      acc[rt] = __builtin_amdgcn_mfma_f32_16x16x32_f16(a[rt], b, acc[rt], 0, 0, 0);
  }
  int col = ct * 16 + mrow;
  float bv = bias[col];
  #pragma unroll
  for (int rt = 0; rt < 4; ++rt)
    #pragma unroll
    for (int reg = 0; reg < 4; ++reg) {
      int row = r0 + rt * 16 + ((lane >> 4) << 2) + reg;
      if (row < N_NODES) y2[(size_t)row * 64 + col] = acc[rt][reg] + bv;
    }
}

// ------------------------------------------------------------------ BatchNorm
__global__ void __launch_bounds__(256) k_bnstats(const float* __restrict__ y, float* __restrict__ part,
                                                 float* __restrict__ partq) {
  __shared__ float ls[256], lq[256];
  int t = threadIdx.x, col = t & 63, rl = t >> 6;
  float s = 0.f, q = 0.f;
  for (int r = blockIdx.x * 4 + rl; r < N_NODES; r += 128 * 4) {
    float v = y[(size_t)r * 64 + col];
    s += v; q += v * v;
  }
  ls[t] = s; lq[t] = q; __syncthreads();
  if (rl == 0) {
    s = ls[col] + ls[64 + col] + ls[128 + col] + ls[192 + col];
    q = lq[col] + lq[64 + col] + lq[128 + col] + lq[192 + col];
    part[blockIdx.x * 64 + col] = s;
    partq[blockIdx.x * 64 + col] = q;
  }
}

__global__ void __launch_bounds__(64) k_bnfinal(const float* __restrict__ part, const float* __restrict__ partq,
                                                const float* __restrict__ g, const float* __restrict__ b,
                                                float* __restrict__ scale, float* __restrict__ shift) {
  int j = threadIdx.x;
  float s = 0.f, q = 0.f;
  for (int i = 0; i < 128; ++i) { s += part[i * 64 + j]; q += partq[i * 64 + j]; }
  float m = s / (float)N_NODES;
  float v = fmaxf(q / (float)N_NODES - m * m, 0.f);
  float sc = g[j] * rsqrtf(v + EPS);
  scale[j] = sc;
  shift[j] = b[j] - m * sc;
}

__global__ void __launch_bounds__(256) k_bnapply(const float* __restrict__ y, const float* __restrict__ scale,
                                                 const float* __restrict__ shift, _Float16* __restrict__ xout) {
  int t = blockIdx.x * 256 + threadIdx.x;  // one thread = 8 cols
  if (t < N_NODES * 8) {
    int g = t & 7;
    const float* s = y + (size_t)t * 8;
    float4 v0 = *(const float4*)s;
    float4 v1 = *(const float4*)(s + 4);
    float4 sc0 = *(const float4*)(scale + g * 8);
    float4 sc1 = *(const float4*)(scale + g * 8 + 4);
    float4 sh0 = *(const float4*)(shift + g * 8);
    float4 sh1 = *(const float4*)(shift + g * 8 + 4);
    half8 h;
    h[0] = (_Float16)fmaxf(v0.x * sc0.x + sh0.x, 0.f);
    h[1] = (_Float16)fmaxf(v0.y * sc0.y + sh0.y, 0.f);
    h[2] = (_Float16)fmaxf(v0.z * sc0.z + sh0.z, 0.f);
    h[3] = (_Float16)fmaxf(v0.w * sc0.w + sh0.w, 0.f);
    h[4] = (_Float16)fmaxf(v1.x * sc1.x + sh1.x, 0.f);
    h[5] = (_Float16)fmaxf(v1.y * sc1.y + sh1.y, 0.f);
    h[6] = (_Float16)fmaxf(v1.z * sc1.z + sh1.z, 0.f);
    h[7] = (_Float16)fmaxf(v1.w * sc1.w + sh1.w, 0.f);
    *(half8*)(xout + (size_t)t * 8) = h;
  }
}

// ------------------------------------------------------------------ pooling + head MLPs
__global__ void __launch_bounds__(256) k_pool(const _Float16* __restrict__ x, const int* __restrict__ batch,
                                              float* __restrict__ gsum, float* __restrict__ gcnt) {
  int t = threadIdx.x, col = t & 63, rl = t >> 6;
  int rbeg = blockIdx.x * 64 + rl * 16;
  int rend = min(rbeg + 16, N_NODES);
  int curg = -1, cr = 0;
  float acc = 0.f;
  for (int r = rbeg; r < rend; ++r) {
    int g = batch[r];
    if (g != curg) {
      if (curg >= 0) {
        atomicAdd(&gsum[curg * 64 + col], acc);
        if (col == 0) atomicAdd(&gcnt[curg], (float)cr);
      }
      curg = g; acc = 0.f; cr = 0;
    }
    acc += (float)x[(size_t)r * 64 + col]; cr++;
  }
  if (curg >= 0) {
    atomicAdd(&gsum[curg * 64 + col], acc);
    if (col == 0) atomicAdd(&gcnt[curg], (float)cr);
  }
}

__global__ void __launch_bounds__(64) k_shared(const float* __restrict__ gsum, const float* __restrict__ gcnt,
                                               const float* __restrict__ W, const float* __restrict__ b,
                                               float* __restrict__ g2) {
  __shared__ float gm[64];
  int g = blockIdx.x, j = threadIdx.x;
  float cv = fmaxf(gcnt[g], 1.f);
  gm[j] = gsum[g * 64 + j] / cv;
  __syncthreads();
  float s = b[j];
  for (int k = 0; k < 64; ++k) s += gm[k] * W[k * 64 + j];
  g2[g * 64 + j] = fmaxf(s, 0.f);
}

__global__ void __launch_bounds__(64) k_heads(const float* __restrict__ g2, const float* __restrict__ hW1,
                                              const float* __restrict__ hb1, const float* __restrict__ hW2,
                                              const float* __restrict__ hb2, const float* __restrict__ hW3,
                                              const float* __restrict__ hb3, float* __restrict__ out) {
  __shared__ float gv[64], h1[50], h2[25];
  int bid = blockIdx.x;
  int g = bid / NHEADS, h = bid % NHEADS;
  int t = threadIdx.x;
  gv[t] = g2[g * 64 + t];
  __syncthreads();
  if (t < 50) {
    float s = hb1[h * 50 + t];
    for (int k = 0; k < 64; ++k) s += gv[k] * hW1[h * 3200 + k * 50 + t];
    h1[t] = fmaxf(s, 0.f);
  }
  __syncthreads();
  if (t < 25) {
    float s = hb2[h * 25 + t];
    for (int k = 0; k < 50; ++k) s += h1[k] * hW2[h * 1250 + k * 25 + t];
    h2[t] = fmaxf(s, 0.f);
  }
  __syncthreads();
  if (t == 0) {
    float s = hb3[h];
    for (int k = 0; k < 25; ++k) s += h2[k] * hW3[h * 25 + k];
    out[g * NHEADS + h] = s;
  }
}

// ------------------------------------------------------------------ launcher
extern "C" void kernel_launch(void* const* d_in, const int* in_sizes, int n_in,
                              void* d_out, int out_size, void* d_ws, size_t ws_size,
                              hipStream_t stream) {
  const float* x0    = (const float*)d_in[0];
  const int*   eidx  = (const int*)d_in[1];
  const int*   batch = (const int*)d_in[2];
  const float* dh    = (const float*)d_in[3];
  const float* preW  = (const float*)d_in[4];
  const float* preb  = (const float*)d_in[5];
  const float* postW = (const float*)d_in[6];
  const float* postb = (const float*)d_in[7];
  const float* linW  = (const float*)d_in[8];
  const float* linb  = (const float*)d_in[9];
  const float* bng   = (const float*)d_in[10];
  const float* bnb   = (const float*)d_in[11];
  const float* shW   = (const float*)d_in[12];
  const float* shb   = (const float*)d_in[13];
  const float* hW1   = (const float*)d_in[14];
  const float* hb1   = (const float*)d_in[15];
  const float* hW2   = (const float*)d_in[16];
  const float* hb2   = (const float*)d_in[17];
  const float* hW3   = (const float*)d_in[18];
  const float* hb3   = (const float*)d_in[19];
  float* out = (float*)d_out;

  char* ws = (char*)d_ws;
  size_t o = 0;
  auto alloc = [&](size_t bytes) {
    char* p = ws + o;
    o = (o + bytes + 255) & ~(size_t)255;
    return p;
  };
  float* scal   = (float*)alloc(8 * 4);
  int* off      = (int*)alloc((N_NODES + 1) * 4);
  int* cnt      = (int*)alloc(N_NODES * 4);
  int* cur      = (int*)alloc(N_NODES * 4);
  int* esrc     = (int*)alloc(N_EDGES * 4);
  int* blks     = (int*)alloc(64 * 4);
  int* blko     = (int*)alloc(64 * 4);
  _Float16* AB16   = (_Float16*)alloc((size_t)N_NODES * 128 * 2 + 256 * 16);
  _Float16* aggr16 = (_Float16*)alloc((size_t)50048 * 256 * 2);
  _Float16* x16a   = (_Float16*)alloc((size_t)N_NODES * 64 * 2 + 256 * 16);
  _Float16* x16b   = (_Float16*)alloc((size_t)N_NODES * 64 * 2 + 256 * 16);
  _Float16* ybuf16 = (_Float16*)alloc((size_t)N_NODES * 64 * 2 + 256 * 16);
  float* y2     = (float*)alloc((size_t)N_NODES * 64 * 4);
  float4* scales = (float4*)alloc((size_t)N_NODES * 16);
  _Float16* preP  = (_Float16*)alloc(3 * 8192 * 2);
  _Float16* postAP = (_Float16*)alloc((size_t)3 * 65536 * 2);
  _Float16* postBP = (_Float16*)alloc(3 * 4096 * 2);
  _Float16* linP   = (_Float16*)alloc(3 * 4096 * 2);
  float* part   = (float*)alloc(128 * 64 * 4);
  float* partq  = (float*)alloc(128 * 64 * 4);
  float* bnsc   = (float*)alloc(64 * 4);
  float* bnsh   = (float*)alloc(64 * 4);
  float* gsum   = (float*)alloc(NGRAPHS * 64 * 4);
  float* gcnt   = (float*)alloc(NGRAPHS * 4);
  float* g2b    = (float*)alloc(NGRAPHS * 64 * 4);

  const int* srcv = eidx;
  const int* dstv = eidx + N_EDGES;

  k_zero_setup<<<256, 256, 0, stream>>>(cnt, cur, gsum, gcnt);
  k_scalars<<<1, 64, 0, stream>>>(dh, in_sizes[3], scal);
  k_hist<<<(N_EDGES + 255) / 256, 256, 0, stream>>>(dstv, cnt);
  k_scan_a<<<49, 256, 0, stream>>>(cnt, off, blks);
  k_scan_b<<<1, 64, 0, stream>>>(blks, blko);
  k_scan_c<<<196, 256, 0, stream>>>(off, blko);
  k_scatter<<<(N_EDGES + 255) / 256, 256, 0, stream>>>(srcv, dstv, off, cur, esrc);
  k_f2h<<<(N_NODES * 8 + 255) / 256, 256, 0, stream>>>(x0, x16a);
  k_pack_pre<<<96, 256, 0, stream>>>(preW, preP);
  k_pack_postA<<<768, 256, 0, stream>>>(postW, postAP);
  k_pack_postB<<<48, 256, 0, stream>>>(postW, postBP);
  k_pack_lin<<<48, 256, 0, stream>>>(linW, linP);

  const _Float16* xc = x16a;
  _Float16* xn[3] = {x16b, x16a, x16b};
  for (int l = 0; l < 3; ++l) {
    k_mfma_g1<<<782, 256, 0, stream>>>(xc, preP + (size_t)l * 8192, preb + l * 64, AB16);
    k_aggr<<<12500, 256, 0, stream>>>(AB16, off, esrc, scal, aggr16, scales);
    k_mfma_g2<<<782, 256, 0, stream>>>(aggr16, xc, postAP + (size_t)l * 65536, postBP + (size_t)l * 4096,
                                       postb + l * 64, scales, ybuf16);
    k_mfma_g3<<<782, 256, 0, stream>>>(ybuf16, linP + (size_t)l * 4096, linb + l * 64, y2);
    k_bnstats<<<128, 256, 0, stream>>>(y2, part, partq);
    k_bnfinal<<<1, 64, 0, stream>>>(part, partq, bng + l * 64, bnb + l * 64, bnsc, bnsh);
    k_bnapply<<<(N_NODES * 8 + 255) / 256, 256, 0, stream>>>(y2, bnsc, bnsh, xn[l]);
    xc = xn[l];
  }
  k_pool<<<782, 256, 0, stream>>>(xc, batch, gsum, gcnt);
  k_shared<<<NGRAPHS, 64, 0, stream>>>(gsum, gcnt, shW, shb, g2b);
  k_heads<<<NGRAPHS * NHEADS, 64, 0, stream>>>(g2b, hW1, hb1, hW2, hb2, hW3, hb3, out);
}

// Round 3
// 583.625 us; speedup vs baseline: 1.5309x; 1.1201x over previous
//
#include <hip/hip_runtime.h>
#include <math.h>

#define N_NODES 50000
#define N_EDGES 800000
#define NGRAPHS 50
#define NHEADS 3
#define EPS 1e-5f
#define NPASS 8
#define PASS_W ((N_NODES + NPASS - 1) / NPASS)

typedef _Float16 half8 __attribute__((ext_vector_type(8)));
typedef float f32x4 __attribute__((ext_vector_type(4)));

// ------------------------------------------------------------------ setup
__global__ void __launch_bounds__(256) k_zero_setup(int* cnt, int* cur, float* gsum, float* gcnt,
                                                    float* part, float* partq) {
  int gid = blockIdx.x * 256 + threadIdx.x;
  int gs = gridDim.x * 256;
  for (int i = gid; i < N_NODES; i += gs) { cnt[i] = 0; cur[i] = 0; }
  for (int i = gid; i < NGRAPHS * 64; i += gs) gsum[i] = 0.f;
  for (int i = gid; i < NGRAPHS; i += gs) gcnt[i] = 0.f;
  for (int i = gid; i < 128 * 64; i += gs) { part[i] = 0.f; partq[i] = 0.f; }
}

__global__ void __launch_bounds__(64) k_scalars(const float* dh, int nbins, float* scal) {
  int t = threadIdx.x;
  float v = (t < nbins) ? dh[t] : 0.f;
  float lv = logf((float)t + 1.f) * v;
  float bv = (float)t * v;
  for (int d = 32; d > 0; d >>= 1) {
    v  += __shfl_down(v,  d, 64);
    lv += __shfl_down(lv, d, 64);
    bv += __shfl_down(bv, d, 64);
  }
  if (t == 0) { scal[0] = lv / v; scal[1] = bv / v; }  // avg_log, avg_lin
}

__global__ void __launch_bounds__(256) k_hist(const int* __restrict__ dst, int* __restrict__ cnt) {
  int e = blockIdx.x * 256 + threadIdx.x;
  if (e < N_EDGES) atomicAdd(&cnt[dst[e]], 1);
}

__global__ void __launch_bounds__(256) k_scan_a(const int* __restrict__ cnt, int* __restrict__ off,
                                                int* __restrict__ blksum) {
  __shared__ int lds[256];
  int t = threadIdx.x;
  int base = blockIdx.x * 1024 + t * 4;
  int v0 = (base + 0 < N_NODES) ? cnt[base + 0] : 0;
  int v1 = (base + 1 < N_NODES) ? cnt[base + 1] : 0;
  int v2 = (base + 2 < N_NODES) ? cnt[base + 2] : 0;
  int v3 = (base + 3 < N_NODES) ? cnt[base + 3] : 0;
  int tsum = v0 + v1 + v2 + v3;
  lds[t] = tsum; __syncthreads();
  for (int d = 1; d < 256; d <<= 1) {
    int x = (t >= d) ? lds[t - d] : 0;
    __syncthreads();
    lds[t] += x;
    __syncthreads();
  }
  int run = lds[t] - tsum;
  if (base + 0 < N_NODES) off[base + 0] = run; run += v0;
  if (base + 1 < N_NODES) off[base + 1] = run; run += v1;
  if (base + 2 < N_NODES) off[base + 2] = run; run += v2;
  if (base + 3 < N_NODES) off[base + 3] = run;
  if (t == 255) blksum[blockIdx.x] = lds[255];
}

__global__ void __launch_bounds__(64) k_scan_b(const int* __restrict__ blksum, int* __restrict__ blkoff) {
  int t = threadIdx.x;
  int own = (t < 49) ? blksum[t] : 0;
  int v = own;
  for (int d = 1; d < 64; d <<= 1) {
    int u = __shfl_up(v, d, 64);
    if (t >= d) v += u;
  }
  if (t < 49) blkoff[t] = v - own;
}

__global__ void __launch_bounds__(256) k_scan_c(int* __restrict__ off, const int* __restrict__ blkoff) {
  int i = blockIdx.x * 256 + threadIdx.x;
  if (i < N_NODES) off[i] += blkoff[i >> 10];
  if (i == 0) off[N_NODES] = N_EDGES;
}

// dst-windowed scatter: pass p only handles dst in [p*PASS_W, (p+1)*PASS_W)
// -> esrc writes confined to a ~400 KB window => lines fill before writeback.
__global__ void __launch_bounds__(256) k_scatter_pass(const int* __restrict__ src, const int* __restrict__ dst,
                                                      const int* __restrict__ off, int* __restrict__ cur,
                                                      int* __restrict__ esrc, int lo, int hi) {
  int e = blockIdx.x * 256 + threadIdx.x;
  if (e < N_EDGES) {
    int d = dst[e];
    if (d >= lo && d < hi) {
      int pos = off[d] + atomicAdd(&cur[d], 1);
      esrc[pos] = src[e];
    }
  }
}

// ------------------------------------------------------------------ fp32 -> fp16 convert (x0)
__global__ void __launch_bounds__(256) k_f2h(const float* __restrict__ xin, _Float16* __restrict__ xout) {
  int t = blockIdx.x * 256 + threadIdx.x;
  if (t < N_NODES * 8) {
    const float* s = xin + (size_t)t * 8;
    float4 v0 = *(const float4*)s;
    float4 v1 = *(const float4*)(s + 4);
    half8 h = {(_Float16)v0.x, (_Float16)v0.y, (_Float16)v0.z, (_Float16)v0.w,
               (_Float16)v1.x, (_Float16)v1.y, (_Float16)v1.z, (_Float16)v1.w};
    *(half8*)(xout + (size_t)t * 8) = h;
  }
}

// ------------------------------------------------------------------ combined weight packing (b-frag order)
// b-frag element (lane, j): k = kbase + (lane>>4)*8 + j, col = cbase + (lane&15)
__global__ void __launch_bounds__(256) k_pack_all(const float* __restrict__ preW, const float* __restrict__ postW,
                                                  const float* __restrict__ linW, _Float16* __restrict__ preP,
                                                  _Float16* __restrict__ postAP, _Float16* __restrict__ postBP,
                                                  _Float16* __restrict__ linP) {
  int t = blockIdx.x * 256 + threadIdx.x;
  if (t < 24576) {  // preP: 3 * 8192
    int l = t >> 13, r = t & 8191;
    int j = r & 7, lane = (r >> 3) & 63, ctg = (r >> 9) & 7, kc = r >> 12;
    int k = kc * 32 + ((lane >> 4) << 3) + j;
    int col = ctg * 16 + (lane & 15);
    const float* W = preW + (size_t)l * 8192;
    float v = (col < 64) ? W[k * 64 + col] : W[(64 + k) * 64 + (col - 64)];
    preP[(size_t)l * 8192 + r] = (_Float16)v;
  } else if (t < 221184) {  // postAP: 3 * 65536
    int q = t - 24576;
    int l = q >> 16, r = q & 65535;
    int j = r & 7, lane = (r >> 3) & 63, ct = (r >> 9) & 3, s = (r >> 11) & 3, kc = r >> 13;
    int k = kc * 32 + ((lane >> 4) << 3) + j;
    int col = ct * 16 + (lane & 15);
    postAP[(size_t)l * 65536 + r] = (_Float16)postW[(size_t)l * 69632 + (size_t)(64 + s * 256 + k) * 64 + col];
  } else if (t < 233472) {  // postBP: 3 * 4096
    int q = t - 221184;
    int l = q >> 12, r = q & 4095;
    int j = r & 7, lane = (r >> 3) & 63, ct = (r >> 9) & 3, kc = r >> 11;
    int k = kc * 32 + ((lane >> 4) << 3) + j;
    int col = ct * 16 + (lane & 15);
    postBP[(size_t)l * 4096 + r] = (_Float16)postW[(size_t)l * 69632 + (size_t)k * 64 + col];
  } else if (t < 245760) {  // linP: 3 * 4096
    int q = t - 233472;
    int l = q >> 12, r = q & 4095;
    int j = r & 7, lane = (r >> 3) & 63, ct = (r >> 9) & 3, kc = r >> 11;
    int k = kc * 32 + ((lane >> 4) << 3) + j;
    int col = ct * 16 + (lane & 15);
    linP[(size_t)l * 4096 + r] = (_Float16)linW[(size_t)l * 4096 + (size_t)k * 64 + col];
  }
}

// ------------------------------------------------------------------ GEMM1 (+fused BN-apply of previous layer)
// yin: fp16 [N,64]. If applyBN: a = relu(yin*sc+sh) (per-column), wave0 also writes transformed x to xout.
__global__ void __launch_bounds__(256) k_mfma_g1(const _Float16* __restrict__ yin, const float* __restrict__ bnsc,
                                                 const float* __restrict__ bnsh, int applyBN,
                                                 const _Float16* __restrict__ wp, const float* __restrict__ bias,
                                                 _Float16* __restrict__ AB, _Float16* __restrict__ xout) {
  int t = threadIdx.x, lane = t & 63, wave = t >> 6;
  int r0 = blockIdx.x * 64;
  int mrow = lane & 15, q8 = ((lane >> 4) << 3);
  f32x4 acc[4][2];
  #pragma unroll
  for (int rt = 0; rt < 4; ++rt) { acc[rt][0] = (f32x4)0.f; acc[rt][1] = (f32x4)0.f; }
  #pragma unroll
  for (int kc = 0; kc < 2; ++kc) {
    int k0 = kc * 32 + q8;
    half8 a[4];
    #pragma unroll
    for (int rt = 0; rt < 4; ++rt) {
      int r = min(r0 + rt * 16 + mrow, N_NODES - 1);
      a[rt] = *(const half8*)(yin + (size_t)r * 64 + k0);
    }
    if (applyBN) {
      float4 sc0 = *(const float4*)(bnsc + k0);
      float4 sc1 = *(const float4*)(bnsc + k0 + 4);
      float4 sh0 = *(const float4*)(bnsh + k0);
      float4 sh1 = *(const float4*)(bnsh + k0 + 4);
      #pragma unroll
      for (int rt = 0; rt < 4; ++rt) {
        half8 v = a[rt];
        v[0] = (_Float16)fmaxf((float)v[0] * sc0.x + sh0.x, 0.f);
        v[1] = (_Float16)fmaxf((float)v[1] * sc0.y + sh0.y, 0.f);
        v[2] = (_Float16)fmaxf((float)v[2] * sc0.z + sh0.z, 0.f);
        v[3] = (_Float16)fmaxf((float)v[3] * sc0.w + sh0.w, 0.f);
        v[4] = (_Float16)fmaxf((float)v[4] * sc1.x + sh1.x, 0.f);
        v[5] = (_Float16)fmaxf((float)v[5] * sc1.y + sh1.y, 0.f);
        v[6] = (_Float16)fmaxf((float)v[6] * sc1.z + sh1.z, 0.f);
        v[7] = (_Float16)fmaxf((float)v[7] * sc1.w + sh1.w, 0.f);
        a[rt] = v;
      }
      if (wave == 0) {  // wave0 covers every (row, k-oct) exactly once over rt x kc
        #pragma unroll
        for (int rt = 0; rt < 4; ++rt) {
          int r = min(r0 + rt * 16 + mrow, N_NODES - 1);
          *(half8*)(xout + (size_t)r * 64 + k0) = a[rt];
        }
      }
    }
    #pragma unroll
    for (int ci = 0; ci < 2; ++ci) {
      int ctg = wave * 2 + ci;
      half8 b = *(const half8*)(wp + (size_t)((kc * 8 + ctg) * 64 + lane) * 8);
      #pragma unroll
      for (int rt = 0; rt < 4; ++rt)
        acc[rt][ci] = __builtin_amdgcn_mfma_f32_16x16x32_f16(a[rt], b, acc[rt][ci], 0, 0, 0);
    }
  }
  #pragma unroll
  for (int ci = 0; ci < 2; ++ci) {
    int col = (wave * 2 + ci) * 16 + mrow;
    float bv = (col < 64) ? bias[col] : 0.f;
    #pragma unroll
    for (int rt = 0; rt < 4; ++rt)
      #pragma unroll
      for (int reg = 0; reg < 4; ++reg) {
        int row = r0 + rt * 16 + ((lane >> 4) << 2) + reg;
        if (row < N_NODES) AB[(size_t)row * 128 + col] = (_Float16)(acc[rt][ci][reg] + bv);
      }
  }
}

// ------------------------------------------------------------------ aggregation (1 wave/node), fp16 in/out
__global__ void __launch_bounds__(256) k_aggr(const _Float16* __restrict__ AB, const int* __restrict__ off,
                                              const int* __restrict__ esrc, const float* __restrict__ scal,
                                              _Float16* __restrict__ aggr, float4* __restrict__ scales) {
  int wave = threadIdx.x >> 6, lane = threadIdx.x & 63;
  int n = blockIdx.x * 4 + wave;
  if (n >= N_NODES) return;
  float c = (float)AB[(size_t)n * 128 + lane];
  int e0 = off[n], e1 = off[n + 1];
  int deg = e1 - e0;
  float sum = 0.f, sq = 0.f, mn = 3.4e38f, mx = -3.4e38f;
  int e = e0;
  for (; e + 1 < e1; e += 2) {
    int s0 = esrc[e], s1 = esrc[e + 1];
    float b0 = (float)AB[(size_t)s0 * 128 + 64 + lane];
    float b1 = (float)AB[(size_t)s1 * 128 + 64 + lane];
    sum += b0 + b1; sq += b0 * b0 + b1 * b1;
    mn = fminf(mn, fminf(b0, b1)); mx = fmaxf(mx, fmaxf(b0, b1));
  }
  if (e < e1) {
    int s = esrc[e];
    float b = (float)AB[(size_t)s * 128 + 64 + lane];
    sum += b; sq += b * b; mn = fminf(mn, b); mx = fmaxf(mx, b);
  }
  _Float16* arow = aggr + (size_t)n * 256;
  if (deg == 0) {
    arow[lane] = (_Float16)0.f; arow[64 + lane] = (_Float16)0.f;
    arow[128 + lane] = (_Float16)0.f; arow[192 + lane] = (_Float16)sqrtf(EPS);
  } else {
    float inv = 1.f / (float)deg;
    float mb = sum * inv, m2 = sq * inv;
    float var = fmaxf(m2 - mb * mb, 0.f);
    arow[lane]       = (_Float16)(c + mb);
    arow[64 + lane]  = (_Float16)(c + mn);
    arow[128 + lane] = (_Float16)(c + mx);
    arow[192 + lane] = (_Float16)sqrtf(var + EPS);
  }
  if (lane == 0) {
    float degf = fmaxf((float)deg, 1.f);
    float ld = logf(degf + 1.f);
    float al = scal[0], av = scal[1];
    scales[n] = make_float4(ld / al, al / ld, degf / av, 0.f);
  }
}

// ------------------------------------------------------------------ GEMM2: y = x@Wx + sum_s scale_s*(aggr@W_s) + postb
__global__ void __launch_bounds__(256) k_mfma_g2(const _Float16* __restrict__ aggr, const _Float16* __restrict__ x16,
                                                 const _Float16* __restrict__ wpA, const _Float16* __restrict__ wpB,
                                                 const float* __restrict__ postb, const float4* __restrict__ scales,
                                                 _Float16* __restrict__ ybuf) {
  int t = threadIdx.x, lane = t & 63, ct = t >> 6;
  int r0 = blockIdx.x * 64;
  int mrow = lane & 15, q8 = ((lane >> 4) << 3);
  f32x4 acc[4][4];  // [rowtile][set]
  #pragma unroll
  for (int rt = 0; rt < 4; ++rt)
    #pragma unroll
    for (int s = 0; s < 4; ++s) acc[rt][s] = (f32x4)0.f;
  #pragma unroll 2
  for (int kc = 0; kc < 8; ++kc) {
    half8 a[4];
    #pragma unroll
    for (int rt = 0; rt < 4; ++rt) {
      int r = min(r0 + rt * 16 + mrow, N_NODES - 1);
      a[rt] = *(const half8*)(aggr + (size_t)r * 256 + kc * 32 + q8);
    }
    #pragma unroll
    for (int s = 0; s < 4; ++s) {
      half8 b = *(const half8*)(wpA + (size_t)((((kc * 4 + s) * 4 + ct) * 64) + lane) * 8);
      #pragma unroll
      for (int rt = 0; rt < 4; ++rt)
        acc[rt][s] = __builtin_amdgcn_mfma_f32_16x16x32_f16(a[rt], b, acc[rt][s], 0, 0, 0);
    }
  }
  #pragma unroll
  for (int kc = 0; kc < 2; ++kc) {
    half8 a[4];
    #pragma unroll
    for (int rt = 0; rt < 4; ++rt) {
      int r = min(r0 + rt * 16 + mrow, N_NODES - 1);
      a[rt] = *(const half8*)(x16 + (size_t)r * 64 + kc * 32 + q8);
    }
    half8 b = *(const half8*)(wpB + (size_t)(((kc * 4 + ct) * 64) + lane) * 8);
    #pragma unroll
    for (int rt = 0; rt < 4; ++rt)
      acc[rt][0] = __builtin_amdgcn_mfma_f32_16x16x32_f16(a[rt], b, acc[rt][0], 0, 0, 0);
  }
  int col = ct * 16 + mrow;
  float pb = postb[col];
  #pragma unroll
  for (int rt = 0; rt < 4; ++rt)
    #pragma unroll
    for (int reg = 0; reg < 4; ++reg) {
      int row = r0 + rt * 16 + ((lane >> 4) << 2) + reg;
      if (row < N_NODES) {
        float4 sc = scales[row];
        float v = acc[rt][0][reg] + sc.x * acc[rt][1][reg] + sc.y * acc[rt][2][reg] + sc.z * acc[rt][3][reg] + pb;
        ybuf[(size_t)row * 64 + col] = (_Float16)v;
      }
    }
}

// ------------------------------------------------------------------ GEMM3 (+fused BN partial stats), fp16 out
__global__ void __launch_bounds__(256) k_mfma_g3(const _Float16* __restrict__ yin, const _Float16* __restrict__ wp,
                                                 const float* __restrict__ bias, _Float16* __restrict__ y16,
                                                 float* __restrict__ part, float* __restrict__ partq) {
  int t = threadIdx.x, lane = t & 63, ct = t >> 6;
  int r0 = blockIdx.x * 64;
  int mrow = lane & 15, q8 = ((lane >> 4) << 3);
  f32x4 acc[4];
  #pragma unroll
  for (int rt = 0; rt < 4; ++rt) acc[rt] = (f32x4)0.f;
  #pragma unroll
  for (int kc = 0; kc < 2; ++kc) {
    half8 a[4];
    #pragma unroll
    for (int rt = 0; rt < 4; ++rt) {
      int r = min(r0 + rt * 16 + mrow, N_NODES - 1);
      a[rt] = *(const half8*)(yin + (size_t)r * 64 + kc * 32 + q8);
    }
    half8 b = *(const half8*)(wp + (size_t)(((kc * 4 + ct) * 64) + lane) * 8);
    #pragma unroll
    for (int rt = 0; rt < 4; ++rt)
      acc[rt] = __builtin_amdgcn_mfma_f32_16x16x32_f16(a[rt], b, acc[rt], 0, 0, 0);
  }
  int col = ct * 16 + mrow;
  float bv = bias[col];
  float s = 0.f, q = 0.f;
  #pragma unroll
  for (int rt = 0; rt < 4; ++rt)
    #pragma unroll
    for (int reg = 0; reg < 4; ++reg) {
      int row = r0 + rt * 16 + ((lane >> 4) << 2) + reg;
      if (row < N_NODES) {
        float v = acc[rt][reg] + bv;
        y16[(size_t)row * 64 + col] = (_Float16)v;
        s += v; q += v * v;
      }
    }
  int slot = (blockIdx.x & 127) * 64 + col;
  atomicAdd(&part[slot], s);
  atomicAdd(&partq[slot], q);
}

__global__ void __launch_bounds__(256) k_bnfinal(float* __restrict__ part, float* __restrict__ partq,
                                                 const float* __restrict__ g, const float* __restrict__ b,
                                                 float* __restrict__ scale, float* __restrict__ shift) {
  __shared__ float ls[256], lq[256];
  int t = threadIdx.x, col = t & 63, qtr = t >> 6;
  float s = 0.f, q = 0.f;
  for (int i = 0; i < 32; ++i) {
    int slot = qtr * 32 + i;
    s += part[slot * 64 + col];
    q += partq[slot * 64 + col];
  }
  ls[t] = s; lq[t] = q; __syncthreads();
  if (t < 64) {
    s = ls[t] + ls[64 + t] + ls[128 + t] + ls[192 + t];
    q = lq[t] + lq[64 + t] + lq[128 + t] + lq[192 + t];
    float m = s / (float)N_NODES;
    float v = fmaxf(q / (float)N_NODES - m * m, 0.f);
    float sc = g[t] * rsqrtf(v + EPS);
    scale[t] = sc;
    shift[t] = b[t] - m * sc;
  }
  __syncthreads();
  for (int i = t; i < 128 * 64; i += 256) { part[i] = 0.f; partq[i] = 0.f; }  // for next layer
}

// ------------------------------------------------------------------ pooling (+fused final BN) + head MLPs
__global__ void __launch_bounds__(256) k_pool(const _Float16* __restrict__ y16, const float* __restrict__ bnsc,
                                              const float* __restrict__ bnsh, const int* __restrict__ batch,
                                              float* __restrict__ gsum, float* __restrict__ gcnt) {
  int t = threadIdx.x, col = t & 63, rl = t >> 6;
  float sc = bnsc[col], sh = bnsh[col];
  int rbeg = blockIdx.x * 64 + rl * 16;
  int rend = min(rbeg + 16, N_NODES);
  int curg = -1, cr = 0;
  float acc = 0.f;
  for (int r = rbeg; r < rend; ++r) {
    int g = batch[r];
    if (g != curg) {
      if (curg >= 0) {
        atomicAdd(&gsum[curg * 64 + col], acc);
        if (col == 0) atomicAdd(&gcnt[curg], (float)cr);
      }
      curg = g; acc = 0.f; cr = 0;
    }
    acc += fmaxf((float)y16[(size_t)r * 64 + col] * sc + sh, 0.f); cr++;
  }
  if (curg >= 0) {
    atomicAdd(&gsum[curg * 64 + col], acc);
    if (col == 0) atomicAdd(&gcnt[curg], (float)cr);
  }
}

__global__ void __launch_bounds__(64) k_shared(const float* __restrict__ gsum, const float* __restrict__ gcnt,
                                               const float* __restrict__ W, const float* __restrict__ b,
                                               float* __restrict__ g2) {
  __shared__ float gm[64];
  int g = blockIdx.x, j = threadIdx.x;
  float cv = fmaxf(gcnt[g], 1.f);
  gm[j] = gsum[g * 64 + j] / cv;
  __syncthreads();
  float s = b[j];
  for (int k = 0; k < 64; ++k) s += gm[k] * W[k * 64 + j];
  g2[g * 64 + j] = fmaxf(s, 0.f);
}

__global__ void __launch_bounds__(64) k_heads(const float* __restrict__ g2, const float* __restrict__ hW1,
                                              const float* __restrict__ hb1, const float* __restrict__ hW2,
                                              const float* __restrict__ hb2, const float* __restrict__ hW3,
                                              const float* __restrict__ hb3, float* __restrict__ out) {
  __shared__ float gv[64], h1[50], h2[25];
  int bid = blockIdx.x;
  int g = bid / NHEADS, h = bid % NHEADS;
  int t = threadIdx.x;
  gv[t] = g2[g * 64 + t];
  __syncthreads();
  if (t < 50) {
    float s = hb1[h * 50 + t];
    for (int k = 0; k < 64; ++k) s += gv[k] * hW1[h * 3200 + k * 50 + t];
    h1[t] = fmaxf(s, 0.f);
  }
  __syncthreads();
  if (t < 25) {
    float s = hb2[h * 25 + t];
    for (int k = 0; k < 50; ++k) s += h1[k] * hW2[h * 1250 + k * 25 + t];
    h2[t] = fmaxf(s, 0.f);
  }
  __syncthreads();
  if (t == 0) {
    float s = hb3[h];
    for (int k = 0; k < 25; ++k) s += h2[k] * hW3[h * 25 + k];
    out[g * NHEADS + h] = s;
  }
}

// ------------------------------------------------------------------ launcher
extern "C" void kernel_launch(void* const* d_in, const int* in_sizes, int n_in,
                              void* d_out, int out_size, void* d_ws, size_t ws_size,
                              hipStream_t stream) {
  const float* x0    = (const float*)d_in[0];
  const int*   eidx  = (const int*)d_in[1];
  const int*   batch = (const int*)d_in[2];
  const float* dh    = (const float*)d_in[3];
  const float* preW  = (const float*)d_in[4];
  const float* preb  = (const float*)d_in[5];
  const float* postW = (const float*)d_in[6];
  const float* postb = (const float*)d_in[7];
  const float* linW  = (const float*)d_in[8];
  const float* linb  = (const float*)d_in[9];
  const float* bng   = (const float*)d_in[10];
  const float* bnb   = (const float*)d_in[11];
  const float* shW   = (const float*)d_in[12];
  const float* shb   = (const float*)d_in[13];
  const float* hW1   = (const float*)d_in[14];
  const float* hb1   = (const float*)d_in[15];
  const float* hW2   = (const float*)d_in[16];
  const float* hb2   = (const float*)d_in[17];
  const float* hW3   = (const float*)d_in[18];
  const float* hb3   = (const float*)d_in[19];
  float* out = (float*)d_out;

  char* ws = (char*)d_ws;
  size_t o = 0;
  auto alloc = [&](size_t bytes) {
    char* p = ws + o;
    o = (o + bytes + 255) & ~(size_t)255;
    return p;
  };
  float* scal   = (float*)alloc(8 * 4);
  int* off      = (int*)alloc((N_NODES + 1) * 4);
  int* cnt      = (int*)alloc(N_NODES * 4);
  int* cur      = (int*)alloc(N_NODES * 4);
  int* esrc     = (int*)alloc(N_EDGES * 4);
  int* blks     = (int*)alloc(64 * 4);
  int* blko     = (int*)alloc(64 * 4);
  _Float16* AB16   = (_Float16*)alloc((size_t)N_NODES * 128 * 2 + 256 * 16);
  _Float16* aggr16 = (_Float16*)alloc((size_t)50048 * 256 * 2);
  _Float16* x16a   = (_Float16*)alloc((size_t)N_NODES * 64 * 2 + 256 * 16);
  _Float16* xbuf   = (_Float16*)alloc((size_t)N_NODES * 64 * 2 + 256 * 16);
  _Float16* ybuf16 = (_Float16*)alloc((size_t)N_NODES * 64 * 2 + 256 * 16);
  _Float16* y16    = (_Float16*)alloc((size_t)N_NODES * 64 * 2 + 256 * 16);
  float4* scales = (float4*)alloc((size_t)N_NODES * 16);
  _Float16* preP   = (_Float16*)alloc(3 * 8192 * 2);
  _Float16* postAP = (_Float16*)alloc((size_t)3 * 65536 * 2);
  _Float16* postBP = (_Float16*)alloc(3 * 4096 * 2);
  _Float16* linP   = (_Float16*)alloc(3 * 4096 * 2);
  float* part   = (float*)alloc(128 * 64 * 4);
  float* partq  = (float*)alloc(128 * 64 * 4);
  float* bnsc   = (float*)alloc(64 * 4);
  float* bnsh   = (float*)alloc(64 * 4);
  float* gsum   = (float*)alloc(NGRAPHS * 64 * 4);
  float* gcnt   = (float*)alloc(NGRAPHS * 4);
  float* g2b    = (float*)alloc(NGRAPHS * 64 * 4);

  const int* srcv = eidx;
  const int* dstv = eidx + N_EDGES;

  k_zero_setup<<<256, 256, 0, stream>>>(cnt, cur, gsum, gcnt, part, partq);
  k_scalars<<<1, 64, 0, stream>>>(dh, in_sizes[3], scal);
  k_hist<<<(N_EDGES + 255) / 256, 256, 0, stream>>>(dstv, cnt);
  k_scan_a<<<49, 256, 0, stream>>>(cnt, off, blks);
  k_scan_b<<<1, 64, 0, stream>>>(blks, blko);
  k_scan_c<<<196, 256, 0, stream>>>(off, blko);
  for (int p = 0; p < NPASS; ++p)
    k_scatter_pass<<<(N_EDGES + 255) / 256, 256, 0, stream>>>(srcv, dstv, off, cur, esrc,
                                                              p * PASS_W, (p + 1) * PASS_W);
  k_f2h<<<(N_NODES * 8 + 255) / 256, 256, 0, stream>>>(x0, x16a);
  k_pack_all<<<960, 256, 0, stream>>>(preW, postW, linW, preP, postAP, postBP, linP);

  for (int l = 0; l < 3; ++l) {
    const _Float16* g1in = (l == 0) ? x16a : y16;
    const _Float16* xc   = (l == 0) ? x16a : xbuf;
    k_mfma_g1<<<782, 256, 0, stream>>>(g1in, bnsc, bnsh, (l > 0) ? 1 : 0,
                                       preP + (size_t)l * 8192, preb + l * 64, AB16, xbuf);
    k_aggr<<<12500, 256, 0, stream>>>(AB16, off, esrc, scal, aggr16, scales);
    k_mfma_g2<<<782, 256, 0, stream>>>(aggr16, xc, postAP + (size_t)l * 65536, postBP + (size_t)l * 4096,
                                       postb + l * 64, scales, ybuf16);
    k_mfma_g3<<<782, 256, 0, stream>>>(ybuf16, linP + (size_t)l * 4096, linb + l * 64, y16, part, partq);
    k_bnfinal<<<1, 256, 0, stream>>>(part, partq, bng + l * 64, bnb + l * 64, bnsc, bnsh);
  }
  k_pool<<<782, 256, 0, stream>>>(y16, bnsc, bnsh, batch, gsum, gcnt);
  k_shared<<<NGRAPHS, 64, 0, stream>>>(gsum, gcnt, shW, shb, g2b);
  k_heads<<<NGRAPHS * NHEADS, 64, 0, stream>>>(g2b, hW1, hb1, hW2, hb2, hW3, hb3, out);
}

// Round 4
// 501.826 us; speedup vs baseline: 1.7805x; 1.1630x over previous
//
#include <hip/hip_runtime.h>
#include <math.h>

#define N_NODES 50000
#define N_EDGES 800000
#define NGRAPHS 50
#define NHEADS 3
#define EPS 1e-5f
#define NPASS 8
#define PASS_W ((N_NODES + NPASS - 1) / NPASS)

typedef _Float16 half8 __attribute__((ext_vector_type(8)));
typedef float f32x4 __attribute__((ext_vector_type(4)));

// ------------------------------------------------------------------ setup (+folded scalars)
__global__ void __launch_bounds__(256) k_zero_setup(int* cnt, int* cur, float* gsum, float* gcnt,
                                                    float* part, float* partq,
                                                    const float* dh, int nbins, float* scal) {
  int gid = blockIdx.x * 256 + threadIdx.x;
  int gs = gridDim.x * 256;
  for (int i = gid; i < N_NODES; i += gs) { cnt[i] = 0; cur[i] = 0; }
  for (int i = gid; i < NGRAPHS * 64; i += gs) gsum[i] = 0.f;
  for (int i = gid; i < NGRAPHS; i += gs) gcnt[i] = 0.f;
  for (int i = gid; i < 128 * 64; i += gs) { part[i] = 0.f; partq[i] = 0.f; }
  if (blockIdx.x == 0 && threadIdx.x < 64) {
    int t = threadIdx.x;
    float v = (t < nbins) ? dh[t] : 0.f;
    float lv = logf((float)t + 1.f) * v;
    float bv = (float)t * v;
    for (int d = 32; d > 0; d >>= 1) {
      v  += __shfl_down(v,  d, 64);
      lv += __shfl_down(lv, d, 64);
      bv += __shfl_down(bv, d, 64);
    }
    if (t == 0) { scal[0] = lv / v; scal[1] = bv / v; }  // avg_log, avg_lin
  }
}

__global__ void __launch_bounds__(256) k_hist(const int* __restrict__ dst, int* __restrict__ cnt) {
  int e = blockIdx.x * 256 + threadIdx.x;
  if (e < N_EDGES) atomicAdd(&cnt[dst[e]], 1);
}

__global__ void __launch_bounds__(256) k_scan_a(const int* __restrict__ cnt, int* __restrict__ off,
                                                int* __restrict__ blksum) {
  __shared__ int lds[256];
  int t = threadIdx.x;
  int base = blockIdx.x * 1024 + t * 4;
  int v0 = (base + 0 < N_NODES) ? cnt[base + 0] : 0;
  int v1 = (base + 1 < N_NODES) ? cnt[base + 1] : 0;
  int v2 = (base + 2 < N_NODES) ? cnt[base + 2] : 0;
  int v3 = (base + 3 < N_NODES) ? cnt[base + 3] : 0;
  int tsum = v0 + v1 + v2 + v3;
  lds[t] = tsum; __syncthreads();
  for (int d = 1; d < 256; d <<= 1) {
    int x = (t >= d) ? lds[t - d] : 0;
    __syncthreads();
    lds[t] += x;
    __syncthreads();
  }
  int run = lds[t] - tsum;
  if (base + 0 < N_NODES) off[base + 0] = run; run += v0;
  if (base + 1 < N_NODES) off[base + 1] = run; run += v1;
  if (base + 2 < N_NODES) off[base + 2] = run; run += v2;
  if (base + 3 < N_NODES) off[base + 3] = run;
  if (t == 255) blksum[blockIdx.x] = lds[255];
}

__global__ void __launch_bounds__(64) k_scan_b(const int* __restrict__ blksum, int* __restrict__ blkoff) {
  int t = threadIdx.x;
  int own = (t < 49) ? blksum[t] : 0;
  int v = own;
  for (int d = 1; d < 64; d <<= 1) {
    int u = __shfl_up(v, d, 64);
    if (t >= d) v += u;
  }
  if (t < 49) blkoff[t] = v - own;
}

__global__ void __launch_bounds__(256) k_scan_c(int* __restrict__ off, const int* __restrict__ blkoff) {
  int i = blockIdx.x * 256 + threadIdx.x;
  if (i < N_NODES) off[i] += blkoff[i >> 10];
  if (i == 0) off[N_NODES] = N_EDGES;
}

// single-kernel dst-windowed scatter: each block holds its edge chunk in regs and
// loops the 8 windows internally -> dst/src read once, esrc writes stay window-local.
// Stores PRE-SCALED byte offsets (src * 128 = row stride of B [N,64] fp16).
__global__ void __launch_bounds__(256) k_scatter(const int* __restrict__ src, const int* __restrict__ dst,
                                                 const int* __restrict__ off, int* __restrict__ cur,
                                                 int* __restrict__ esrc) {
  int e = blockIdx.x * 256 + threadIdx.x;
  if (e >= N_EDGES) return;
  int d = dst[e];
  int sv = src[e] << 7;
  #pragma unroll 1
  for (int p = 0; p < NPASS; ++p) {
    int lo = p * PASS_W;
    if (d >= lo && d < lo + PASS_W) {
      int pos = off[d] + atomicAdd(&cur[d], 1);
      esrc[pos] = sv;
    }
  }
}

// ------------------------------------------------------------------ f2h + weight packing (b-frag order)
// b-frag element (lane, j): k = kbase + (lane>>4)*8 + j, col = cbase + (lane&15)
__global__ void __launch_bounds__(256) k_prep(const float* __restrict__ xin, _Float16* __restrict__ xout,
                                              const float* __restrict__ preW, const float* __restrict__ postW,
                                              const float* __restrict__ linW, _Float16* __restrict__ preP,
                                              _Float16* __restrict__ postAP, _Float16* __restrict__ postBP,
                                              _Float16* __restrict__ linP) {
  int t0 = blockIdx.x * 256 + threadIdx.x;
  if (t0 < 400000) {  // f2h: one thread = 8 elems
    const float* s = xin + (size_t)t0 * 8;
    float4 v0 = *(const float4*)s;
    float4 v1 = *(const float4*)(s + 4);
    half8 h = {(_Float16)v0.x, (_Float16)v0.y, (_Float16)v0.z, (_Float16)v0.w,
               (_Float16)v1.x, (_Float16)v1.y, (_Float16)v1.z, (_Float16)v1.w};
    *(half8*)(xout + (size_t)t0 * 8) = h;
    return;
  }
  int t = t0 - 400000;
  if (t < 24576) {  // preP: 3 * 8192
    int l = t >> 13, r = t & 8191;
    int j = r & 7, lane = (r >> 3) & 63, ctg = (r >> 9) & 7, kc = r >> 12;
    int k = kc * 32 + ((lane >> 4) << 3) + j;
    int col = ctg * 16 + (lane & 15);
    const float* W = preW + (size_t)l * 8192;
    float v = (col < 64) ? W[k * 64 + col] : W[(64 + k) * 64 + (col - 64)];
    preP[(size_t)l * 8192 + r] = (_Float16)v;
  } else if (t < 221184) {  // postAP: 3 * 65536
    int q = t - 24576;
    int l = q >> 16, r = q & 65535;
    int j = r & 7, lane = (r >> 3) & 63, ct = (r >> 9) & 3, s = (r >> 11) & 3, kc = r >> 13;
    int k = kc * 32 + ((lane >> 4) << 3) + j;
    int col = ct * 16 + (lane & 15);
    postAP[(size_t)l * 65536 + r] = (_Float16)postW[(size_t)l * 69632 + (size_t)(64 + s * 256 + k) * 64 + col];
  } else if (t < 233472) {  // postBP: 3 * 4096
    int q = t - 221184;
    int l = q >> 12, r = q & 4095;
    int j = r & 7, lane = (r >> 3) & 63, ct = (r >> 9) & 3, kc = r >> 11;
    int k = kc * 32 + ((lane >> 4) << 3) + j;
    int col = ct * 16 + (lane & 15);
    postBP[(size_t)l * 4096 + r] = (_Float16)postW[(size_t)l * 69632 + (size_t)k * 64 + col];
  } else if (t < 245760) {  // linP: 3 * 4096
    int q = t - 233472;
    int l = q >> 12, r = q & 4095;
    int j = r & 7, lane = (r >> 3) & 63, ct = (r >> 9) & 3, kc = r >> 11;
    int k = kc * 32 + ((lane >> 4) << 3) + j;
    int col = ct * 16 + (lane & 15);
    linP[(size_t)l * 4096 + r] = (_Float16)linW[(size_t)l * 4096 + (size_t)k * 64 + col];
  }
}

// ------------------------------------------------------------------ GEMM1 (+fused BN-apply of previous layer)
// Writes A [N,64] (cols 0-63 incl. preb) and B [N,64] (cols 64-127, no bias) separately.
__global__ void __launch_bounds__(256) k_mfma_g1(const _Float16* __restrict__ yin, const float* __restrict__ bnsc,
                                                 const float* __restrict__ bnsh, int applyBN,
                                                 const _Float16* __restrict__ wp, const float* __restrict__ bias,
                                                 _Float16* __restrict__ Aout, _Float16* __restrict__ Bout,
                                                 _Float16* __restrict__ xout) {
  int t = threadIdx.x, lane = t & 63, wave = t >> 6;
  int r0 = blockIdx.x * 64;
  int mrow = lane & 15, q8 = ((lane >> 4) << 3);
  f32x4 acc[4][2];
  #pragma unroll
  for (int rt = 0; rt < 4; ++rt) { acc[rt][0] = (f32x4)0.f; acc[rt][1] = (f32x4)0.f; }
  #pragma unroll
  for (int kc = 0; kc < 2; ++kc) {
    int k0 = kc * 32 + q8;
    half8 a[4];
    #pragma unroll
    for (int rt = 0; rt < 4; ++rt) {
      int r = min(r0 + rt * 16 + mrow, N_NODES - 1);
      a[rt] = *(const half8*)(yin + (size_t)r * 64 + k0);
    }
    if (applyBN) {
      float4 sc0 = *(const float4*)(bnsc + k0);
      float4 sc1 = *(const float4*)(bnsc + k0 + 4);
      float4 sh0 = *(const float4*)(bnsh + k0);
      float4 sh1 = *(const float4*)(bnsh + k0 + 4);
      #pragma unroll
      for (int rt = 0; rt < 4; ++rt) {
        half8 v = a[rt];
        v[0] = (_Float16)fmaxf((float)v[0] * sc0.x + sh0.x, 0.f);
        v[1] = (_Float16)fmaxf((float)v[1] * sc0.y + sh0.y, 0.f);
        v[2] = (_Float16)fmaxf((float)v[2] * sc0.z + sh0.z, 0.f);
        v[3] = (_Float16)fmaxf((float)v[3] * sc0.w + sh0.w, 0.f);
        v[4] = (_Float16)fmaxf((float)v[4] * sc1.x + sh1.x, 0.f);
        v[5] = (_Float16)fmaxf((float)v[5] * sc1.y + sh1.y, 0.f);
        v[6] = (_Float16)fmaxf((float)v[6] * sc1.z + sh1.z, 0.f);
        v[7] = (_Float16)fmaxf((float)v[7] * sc1.w + sh1.w, 0.f);
        a[rt] = v;
      }
      if (wave == 0) {
        #pragma unroll
        for (int rt = 0; rt < 4; ++rt) {
          int r = min(r0 + rt * 16 + mrow, N_NODES - 1);
          *(half8*)(xout + (size_t)r * 64 + k0) = a[rt];
        }
      }
    }
    #pragma unroll
    for (int ci = 0; ci < 2; ++ci) {
      int ctg = wave * 2 + ci;
      half8 b = *(const half8*)(wp + (size_t)((kc * 8 + ctg) * 64 + lane) * 8);
      #pragma unroll
      for (int rt = 0; rt < 4; ++rt)
        acc[rt][ci] = __builtin_amdgcn_mfma_f32_16x16x32_f16(a[rt], b, acc[rt][ci], 0, 0, 0);
    }
  }
  #pragma unroll
  for (int ci = 0; ci < 2; ++ci) {
    int col = (wave * 2 + ci) * 16 + mrow;
    bool isA = col < 64;
    float bv = isA ? bias[col] : 0.f;
    _Float16* outp = isA ? (Aout + col) : (Bout + (col - 64));
    #pragma unroll
    for (int rt = 0; rt < 4; ++rt)
      #pragma unroll
      for (int reg = 0; reg < 4; ++reg) {
        int row = r0 + rt * 16 + ((lane >> 4) << 2) + reg;
        if (row < N_NODES) outp[(size_t)row * 64] = (_Float16)(acc[rt][ci][reg] + bv);
      }
  }
}

// ------------------------------------------------------------------ aggregation (1 wave/node)
// esrc holds byte offsets (src*128). Row base forced wave-uniform -> SGPR-based gathers.
__global__ void __launch_bounds__(256) k_aggr(const _Float16* __restrict__ A, const _Float16* __restrict__ B,
                                              const int* __restrict__ off, const int* __restrict__ esrc,
                                              const float* __restrict__ scal, _Float16* __restrict__ aggr,
                                              float4* __restrict__ scales) {
  int wave = threadIdx.x >> 6, lane = threadIdx.x & 63;
  int n = blockIdx.x * 4 + wave;
  float c = (float)A[(size_t)n * 64 + lane];
  int e0 = __builtin_amdgcn_readfirstlane(off[n]);
  int e1 = __builtin_amdgcn_readfirstlane(off[n + 1]);
  int deg = e1 - e0;
  const char* Bb = (const char*)B;
  int lo2 = lane * 2;
  float sum = 0.f, sq = 0.f, mn = 3.4e38f, mx = -3.4e38f;
  int e = e0;
  for (; e + 3 < e1; e += 4) {
    int r0 = __builtin_amdgcn_readfirstlane(esrc[e]);
    int r1 = __builtin_amdgcn_readfirstlane(esrc[e + 1]);
    int r2 = __builtin_amdgcn_readfirstlane(esrc[e + 2]);
    int r3 = __builtin_amdgcn_readfirstlane(esrc[e + 3]);
    float b0 = (float)*(const _Float16*)(Bb + r0 + lo2);
    float b1 = (float)*(const _Float16*)(Bb + r1 + lo2);
    float b2 = (float)*(const _Float16*)(Bb + r2 + lo2);
    float b3 = (float)*(const _Float16*)(Bb + r3 + lo2);
    sum += (b0 + b1) + (b2 + b3);
    sq += b0 * b0; sq += b1 * b1; sq += b2 * b2; sq += b3 * b3;
    mn = fminf(mn, fminf(fminf(b0, b1), fminf(b2, b3)));
    mx = fmaxf(mx, fmaxf(fmaxf(b0, b1), fmaxf(b2, b3)));
  }
  for (; e < e1; ++e) {
    int r = __builtin_amdgcn_readfirstlane(esrc[e]);
    float b = (float)*(const _Float16*)(Bb + r + lo2);
    sum += b; sq += b * b; mn = fminf(mn, b); mx = fmaxf(mx, b);
  }
  _Float16* arow = aggr + (size_t)n * 256;
  if (deg == 0) {
    arow[lane] = (_Float16)0.f; arow[64 + lane] = (_Float16)0.f;
    arow[128 + lane] = (_Float16)0.f; arow[192 + lane] = (_Float16)sqrtf(EPS);
  } else {
    float inv = 1.f / (float)deg;
    float mb = sum * inv, m2 = sq * inv;
    float var = fmaxf(m2 - mb * mb, 0.f);
    arow[lane]       = (_Float16)(c + mb);
    arow[64 + lane]  = (_Float16)(c + mn);
    arow[128 + lane] = (_Float16)(c + mx);
    arow[192 + lane] = (_Float16)sqrtf(var + EPS);
  }
  if (lane == 0) {
    float degf = fmaxf((float)deg, 1.f);
    float ld = logf(degf + 1.f);
    float al = scal[0], av = scal[1];
    scales[n] = make_float4(ld / al, al / ld, degf / av, 0.f);
  }
}

// ------------------------------------------------------------------ GEMM2: y = x@Wx + sum_s scale_s*(aggr@W_s) + postb
__global__ void __launch_bounds__(256) k_mfma_g2(const _Float16* __restrict__ aggr, const _Float16* __restrict__ x16,
                                                 const _Float16* __restrict__ wpA, const _Float16* __restrict__ wpB,
                                                 const float* __restrict__ postb, const float4* __restrict__ scales,
                                                 _Float16* __restrict__ ybuf) {
  int t = threadIdx.x, lane = t & 63, ct = t >> 6;
  int r0 = blockIdx.x * 64;
  int mrow = lane & 15, q8 = ((lane >> 4) << 3);
  f32x4 acc[4][4];  // [rowtile][set]
  #pragma unroll
  for (int rt = 0; rt < 4; ++rt)
    #pragma unroll
    for (int s = 0; s < 4; ++s) acc[rt][s] = (f32x4)0.f;
  #pragma unroll 2
  for (int kc = 0; kc < 8; ++kc) {
    half8 a[4];
    #pragma unroll
    for (int rt = 0; rt < 4; ++rt) {
      int r = min(r0 + rt * 16 + mrow, N_NODES - 1);
      a[rt] = *(const half8*)(aggr + (size_t)r * 256 + kc * 32 + q8);
    }
    #pragma unroll
    for (int s = 0; s < 4; ++s) {
      half8 b = *(const half8*)(wpA + (size_t)((((kc * 4 + s) * 4 + ct) * 64) + lane) * 8);
      #pragma unroll
      for (int rt = 0; rt < 4; ++rt)
        acc[rt][s] = __builtin_amdgcn_mfma_f32_16x16x32_f16(a[rt], b, acc[rt][s], 0, 0, 0);
    }
  }
  #pragma unroll
  for (int kc = 0; kc < 2; ++kc) {
    half8 a[4];
    #pragma unroll
    for (int rt = 0; rt < 4; ++rt) {
      int r = min(r0 + rt * 16 + mrow, N_NODES - 1);
      a[rt] = *(const half8*)(x16 + (size_t)r * 64 + kc * 32 + q8);
    }
    half8 b = *(const half8*)(wpB + (size_t)(((kc * 4 + ct) * 64) + lane) * 8);
    #pragma unroll
    for (int rt = 0; rt < 4; ++rt)
      acc[rt][0] = __builtin_amdgcn_mfma_f32_16x16x32_f16(a[rt], b, acc[rt][0], 0, 0, 0);
  }
  int col = ct * 16 + mrow;
  float pb = postb[col];
  #pragma unroll
  for (int rt = 0; rt < 4; ++rt)
    #pragma unroll
    for (int reg = 0; reg < 4; ++reg) {
      int row = r0 + rt * 16 + ((lane >> 4) << 2) + reg;
      if (row < N_NODES) {
        float4 sc = scales[row];
        float v = acc[rt][0][reg] + sc.x * acc[rt][1][reg] + sc.y * acc[rt][2][reg] + sc.z * acc[rt][3][reg] + pb;
        ybuf[(size_t)row * 64 + col] = (_Float16)v;
      }
    }
}

// ------------------------------------------------------------------ GEMM3 (+fused BN partial stats), fp16 out
__global__ void __launch_bounds__(256) k_mfma_g3(const _Float16* __restrict__ yin, const _Float16* __restrict__ wp,
                                                 const float* __restrict__ bias, _Float16* __restrict__ y16,
                                                 float* __restrict__ part, float* __restrict__ partq) {
  int t = threadIdx.x, lane = t & 63, ct = t >> 6;
  int r0 = blockIdx.x * 64;
  int mrow = lane & 15, q8 = ((lane >> 4) << 3);
  f32x4 acc[4];
  #pragma unroll
  for (int rt = 0; rt < 4; ++rt) acc[rt] = (f32x4)0.f;
  #pragma unroll
  for (int kc = 0; kc < 2; ++kc) {
    half8 a[4];
    #pragma unroll
    for (int rt = 0; rt < 4; ++rt) {
      int r = min(r0 + rt * 16 + mrow, N_NODES - 1);
      a[rt] = *(const half8*)(yin + (size_t)r * 64 + kc * 32 + q8);
    }
    half8 b = *(const half8*)(wp + (size_t)(((kc * 4 + ct) * 64) + lane) * 8);
    #pragma unroll
    for (int rt = 0; rt < 4; ++rt)
      acc[rt] = __builtin_amdgcn_mfma_f32_16x16x32_f16(a[rt], b, acc[rt], 0, 0, 0);
  }
  int col = ct * 16 + mrow;
  float bv = bias[col];
  float s = 0.f, q = 0.f;
  #pragma unroll
  for (int rt = 0; rt < 4; ++rt)
    #pragma unroll
    for (int reg = 0; reg < 4; ++reg) {
      int row = r0 + rt * 16 + ((lane >> 4) << 2) + reg;
      if (row < N_NODES) {
        float v = acc[rt][reg] + bv;
        y16[(size_t)row * 64 + col] = (_Float16)v;
        s += v; q += v * v;
      }
    }
  int slot = (blockIdx.x & 127) * 64 + col;
  atomicAdd(&part[slot], s);
  atomicAdd(&partq[slot], q);
}

__global__ void __launch_bounds__(256) k_bnfinal(float* __restrict__ part, float* __restrict__ partq,
                                                 const float* __restrict__ g, const float* __restrict__ b,
                                                 float* __restrict__ scale, float* __restrict__ shift) {
  __shared__ float ls[256], lq[256];
  int t = threadIdx.x, col = t & 63, qtr = t >> 6;
  float s = 0.f, q = 0.f;
  for (int i = 0; i < 32; ++i) {
    int slot = qtr * 32 + i;
    s += part[slot * 64 + col];
    q += partq[slot * 64 + col];
  }
  ls[t] = s; lq[t] = q; __syncthreads();
  if (t < 64) {
    s = ls[t] + ls[64 + t] + ls[128 + t] + ls[192 + t];
    q = lq[t] + lq[64 + t] + lq[128 + t] + lq[192 + t];
    float m = s / (float)N_NODES;
    float v = fmaxf(q / (float)N_NODES - m * m, 0.f);
    float sc = g[t] * rsqrtf(v + EPS);
    scale[t] = sc;
    shift[t] = b[t] - m * sc;
  }
  __syncthreads();
  for (int i = t; i < 128 * 64; i += 256) { part[i] = 0.f; partq[i] = 0.f; }
}

// ------------------------------------------------------------------ pooling (+fused final BN) + head MLPs
__global__ void __launch_bounds__(256) k_pool(const _Float16* __restrict__ y16, const float* __restrict__ bnsc,
                                              const float* __restrict__ bnsh, const int* __restrict__ batch,
                                              float* __restrict__ gsum, float* __restrict__ gcnt) {
  int t = threadIdx.x, col = t & 63, rl = t >> 6;
  float sc = bnsc[col], sh = bnsh[col];
  int rbeg = blockIdx.x * 64 + rl * 16;
  int rend = min(rbeg + 16, N_NODES);
  int curg = -1, cr = 0;
  float acc = 0.f;
  for (int r = rbeg; r < rend; ++r) {
    int g = batch[r];
    if (g != curg) {
      if (curg >= 0) {
        atomicAdd(&gsum[curg * 64 + col], acc);
        if (col == 0) atomicAdd(&gcnt[curg], (float)cr);
      }
      curg = g; acc = 0.f; cr = 0;
    }
    acc += fmaxf((float)y16[(size_t)r * 64 + col] * sc + sh, 0.f); cr++;
  }
  if (curg >= 0) {
    atomicAdd(&gsum[curg * 64 + col], acc);
    if (col == 0) atomicAdd(&gcnt[curg], (float)cr);
  }
}

__global__ void __launch_bounds__(64) k_shared(const float* __restrict__ gsum, const float* __restrict__ gcnt,
                                               const float* __restrict__ W, const float* __restrict__ b,
                                               float* __restrict__ g2) {
  __shared__ float gm[64];
  int g = blockIdx.x, j = threadIdx.x;
  float cv = fmaxf(gcnt[g], 1.f);
  gm[j] = gsum[g * 64 + j] / cv;
  __syncthreads();
  float s = b[j];
  for (int k = 0; k < 64; ++k) s += gm[k] * W[k * 64 + j];
  g2[g * 64 + j] = fmaxf(s, 0.f);
}

__global__ void __launch_bounds__(64) k_heads(const float* __restrict__ g2, const float* __restrict__ hW1,
                                              const float* __restrict__ hb1, const float* __restrict__ hW2,
                                              const float* __restrict__ hb2, const float* __restrict__ hW3,
                                              const float* __restrict__ hb3, float* __restrict__ out) {
  __shared__ float gv[64], h1[50], h2[25];
  int bid = blockIdx.x;
  int g = bid / NHEADS, h = bid % NHEADS;
  int t = threadIdx.x;
  gv[t] = g2[g * 64 + t];
  __syncthreads();
  if (t < 50) {
    float s = hb1[h * 50 + t];
    for (int k = 0; k < 64; ++k) s += gv[k] * hW1[h * 3200 + k * 50 + t];
    h1[t] = fmaxf(s, 0.f);
  }
  __syncthreads();
  if (t < 25) {
    float s = hb2[h * 25 + t];
    for (int k = 0; k < 50; ++k) s += h1[k] * hW2[h * 1250 + k * 25 + t];
    h2[t] = fmaxf(s, 0.f);
  }
  __syncthreads();
  if (t == 0) {
    float s = hb3[h];
    for (int k = 0; k < 25; ++k) s += h2[k] * hW3[h * 25 + k];
    out[g * NHEADS + h] = s;
  }
}

// ------------------------------------------------------------------ launcher
extern "C" void kernel_launch(void* const* d_in, const int* in_sizes, int n_in,
                              void* d_out, int out_size, void* d_ws, size_t ws_size,
                              hipStream_t stream) {
  const float* x0    = (const float*)d_in[0];
  const int*   eidx  = (const int*)d_in[1];
  const int*   batch = (const int*)d_in[2];
  const float* dh    = (const float*)d_in[3];
  const float* preW  = (const float*)d_in[4];
  const float* preb  = (const float*)d_in[5];
  const float* postW = (const float*)d_in[6];
  const float* postb = (const float*)d_in[7];
  const float* linW  = (const float*)d_in[8];
  const float* linb  = (const float*)d_in[9];
  const float* bng   = (const float*)d_in[10];
  const float* bnb   = (const float*)d_in[11];
  const float* shW   = (const float*)d_in[12];
  const float* shb   = (const float*)d_in[13];
  const float* hW1   = (const float*)d_in[14];
  const float* hb1   = (const float*)d_in[15];
  const float* hW2   = (const float*)d_in[16];
  const float* hb2   = (const float*)d_in[17];
  const float* hW3   = (const float*)d_in[18];
  const float* hb3   = (const float*)d_in[19];
  float* out = (float*)d_out;

  char* ws = (char*)d_ws;
  size_t o = 0;
  auto alloc = [&](size_t bytes) {
    char* p = ws + o;
    o = (o + bytes + 255) & ~(size_t)255;
    return p;
  };
  float* scal   = (float*)alloc(8 * 4);
  int* off      = (int*)alloc((N_NODES + 1) * 4);
  int* cnt      = (int*)alloc(N_NODES * 4);
  int* cur      = (int*)alloc(N_NODES * 4);
  int* esrc     = (int*)alloc(N_EDGES * 4);
  int* blks     = (int*)alloc(64 * 4);
  int* blko     = (int*)alloc(64 * 4);
  _Float16* A16    = (_Float16*)alloc((size_t)N_NODES * 64 * 2 + 256 * 16);
  _Float16* B16    = (_Float16*)alloc((size_t)N_NODES * 64 * 2 + 256 * 16);
  _Float16* aggr16 = (_Float16*)alloc((size_t)50048 * 256 * 2);
  _Float16* x16a   = (_Float16*)alloc((size_t)N_NODES * 64 * 2 + 256 * 16);
  _Float16* xbuf   = (_Float16*)alloc((size_t)N_NODES * 64 * 2 + 256 * 16);
  _Float16* ybuf16 = (_Float16*)alloc((size_t)N_NODES * 64 * 2 + 256 * 16);
  _Float16* y16    = (_Float16*)alloc((size_t)N_NODES * 64 * 2 + 256 * 16);
  float4* scales = (float4*)alloc((size_t)N_NODES * 16);
  _Float16* preP   = (_Float16*)alloc(3 * 8192 * 2);
  _Float16* postAP = (_Float16*)alloc((size_t)3 * 65536 * 2);
  _Float16* postBP = (_Float16*)alloc(3 * 4096 * 2);
  _Float16* linP   = (_Float16*)alloc(3 * 4096 * 2);
  float* part   = (float*)alloc(128 * 64 * 4);
  float* partq  = (float*)alloc(128 * 64 * 4);
  float* bnsc   = (float*)alloc(64 * 4);
  float* bnsh   = (float*)alloc(64 * 4);
  float* gsum   = (float*)alloc(NGRAPHS * 64 * 4);
  float* gcnt   = (float*)alloc(NGRAPHS * 4);
  float* g2b    = (float*)alloc(NGRAPHS * 64 * 4);

  const int* srcv = eidx;
  const int* dstv = eidx + N_EDGES;

  k_zero_setup<<<256, 256, 0, stream>>>(cnt, cur, gsum, gcnt, part, partq, dh, in_sizes[3], scal);
  k_hist<<<(N_EDGES + 255) / 256, 256, 0, stream>>>(dstv, cnt);
  k_scan_a<<<49, 256, 0, stream>>>(cnt, off, blks);
  k_scan_b<<<1, 64, 0, stream>>>(blks, blko);
  k_scan_c<<<196, 256, 0, stream>>>(off, blko);
  k_scatter<<<(N_EDGES + 255) / 256, 256, 0, stream>>>(srcv, dstv, off, cur, esrc);
  k_prep<<<(400000 + 245760 + 255) / 256, 256, 0, stream>>>(x0, x16a, preW, postW, linW,
                                                            preP, postAP, postBP, linP);

  for (int l = 0; l < 3; ++l) {
    const _Float16* g1in = (l == 0) ? x16a : y16;
    const _Float16* xc   = (l == 0) ? x16a : xbuf;
    k_mfma_g1<<<782, 256, 0, stream>>>(g1in, bnsc, bnsh, (l > 0) ? 1 : 0,
                                       preP + (size_t)l * 8192, preb + l * 64, A16, B16, xbuf);
    k_aggr<<<12500, 256, 0, stream>>>(A16, B16, off, esrc, scal, aggr16, scales);
    k_mfma_g2<<<782, 256, 0, stream>>>(aggr16, xc, postAP + (size_t)l * 65536, postBP + (size_t)l * 4096,
                                       postb + l * 64, scales, ybuf16);
    k_mfma_g3<<<782, 256, 0, stream>>>(ybuf16, linP + (size_t)l * 4096, linb + l * 64, y16, part, partq);
    k_bnfinal<<<1, 256, 0, stream>>>(part, partq, bng + l * 64, bnb + l * 64, bnsc, bnsh);
  }
  k_pool<<<782, 256, 0, stream>>>(y16, bnsc, bnsh, batch, gsum, gcnt);
  k_shared<<<NGRAPHS, 64, 0, stream>>>(gsum, gcnt, shW, shb, g2b);
  k_heads<<<NGRAPHS * NHEADS, 64, 0, stream>>>(g2b, hW1, hb1, hW2, hb2, hW3, hb3, out);
}